// Round 7
// baseline (1110.094 us; speedup 1.0000x reference)
//
#include <hip/hip_runtime.h>
#include <cmath>

// LightGlue forward. All GEMMs + attention in bf16 MFMA. Q/K/V written bf16
// head-major directly by the qkv GEMM epilogue (RoPE fused via lane-shuffle).
// msg stored bf16. Wo folded into W1 (Wf = Wo@W1b). Residual stream: fp32 x
// + bf16 mirror xb. LN+GELU+FFN2 fused into ONE kernel (ffn2f_k): block owns
// 16 rows x all 256 output cols, LN stats block-local, GELU applied once,
// h stored in LDS in MFMA-A layout, W2 read direct from L2.
// NOTE (journal): cooperative mega-kernel with grid.sync() measured 430 us
// per layer-half on MI355X (grid-wide sync ~100 us at 512 WGs) — abandoned.
// N=1024, D=256, H=4, DH=64, L=9. Batched over both images (M=2048).
#define NTOK 1024
#define DM   256
#define NH   4
#define DH   64
#define NL   9

typedef __attribute__((ext_vector_type(8))) __bf16 bf16x8;
typedef __attribute__((ext_vector_type(4))) __bf16 bf16x4;
typedef __attribute__((ext_vector_type(4))) float  f32x4;

__device__ __forceinline__ float logsigf(float x) {
    return fminf(x, 0.0f) - log1pf(expf(-fabsf(x)));
}

__device__ __forceinline__ __bf16 f2bf(float f) {
    unsigned u = __float_as_uint(f);
    u = (u + 0x7FFFu + ((u >> 16) & 1u)) >> 16;          // round-nearest-even
    unsigned short s = (unsigned short)u;
    return __builtin_bit_cast(__bf16, s);
}

// ---------------------------------------------------------------------------
// All weight transposes in ONE dispatch. fp32 [K][N] (batched) -> bf16 [N][K].
// For the qkv group (z<9) output rows are PERMUTED: n' = t*256 + h*64 + d
// (orig n = h*192 + d*3 + t) so the GEMM tile maps 1:1 to (type, head).
// Grid (24, 16, 82).
// ---------------------------------------------------------------------------
__global__ __launch_bounds__(256) void wtrans_all_k(
    const float* __restrict__ sWqkv, const float* __restrict__ sWo,
    const float* __restrict__ sfW1,  const float* __restrict__ sfW2,
    const float* __restrict__ cWqk,  const float* __restrict__ cWv,
    const float* __restrict__ cWo,   const float* __restrict__ cfW1,
    const float* __restrict__ cfW2,  const float* __restrict__ mWp,
    __bf16* __restrict__ wb)
{
    const int z = blockIdx.z;
    const float* src; __bf16* dst; int K, N, b;
    if      (z <  9) { src = sWqkv; dst = wb;            K = 256; N = 768; b = z;      }
    else if (z < 18) { src = sWo;   dst = wb + 1769472;  K = 256; N = 256; b = z - 9;  }
    else if (z < 27) { src = sfW1;  dst = wb + 2359296;  K = 512; N = 512; b = z - 18; }
    else if (z < 36) { src = sfW2;  dst = wb + 4718592;  K = 512; N = 256; b = z - 27; }
    else if (z < 45) { src = cWqk;  dst = wb + 5898240;  K = 256; N = 256; b = z - 36; }
    else if (z < 54) { src = cWv;   dst = wb + 6488064;  K = 256; N = 256; b = z - 45; }
    else if (z < 63) { src = cWo;   dst = wb + 7077888;  K = 256; N = 256; b = z - 54; }
    else if (z < 72) { src = cfW1;  dst = wb + 7667712;  K = 512; N = 512; b = z - 63; }
    else if (z < 81) { src = cfW2;  dst = wb + 10027008; K = 512; N = 256; b = z - 72; }
    else             { src = mWp;   dst = wb + 11206656; K = 256; N = 256; b = 0;      }
    const int n0 = blockIdx.x * 32, k0 = blockIdx.y * 32;
    if (n0 >= N || k0 >= K) return;
    src += (size_t)b * K * N;
    dst += (size_t)b * K * N;

    __shared__ __bf16 t[32][36];
    const int tx = threadIdx.x & 31, ty = threadIdx.x >> 5;
    #pragma unroll
    for (int i = 0; i < 4; ++i) {
        int k = ty + i * 8;
        t[tx][k] = f2bf(src[(size_t)(k0 + k) * N + n0 + tx]);
    }
    __syncthreads();
    const int nr = threadIdx.x >> 3, kc = (threadIdx.x & 7) * 4;
    bf16x4 v = *(const bf16x4*)&t[nr][kc];
    int outr = n0 + nr;
    if (z < 9) {
        int h = outr / 192, r = outr % 192;
        outr = (r % 3) * 256 + h * 64 + (r / 3);
    }
    *(bf16x4*)&dst[(size_t)outr * K + k0 + kc] = v;
}

// ---------------------------------------------------------------------------
// Weight fusion: tW1f[z][o][0:256] = tW1[z][o][0:256] (copy, bx<4);
// tW1f[z][o][256+k] = sum_m tW1[z][o][256+m] * tWo[z][m][k]  (bx>=4, MFMA).
// ---------------------------------------------------------------------------
__global__ __launch_bounds__(256) void wfuse_k(
    const __bf16* __restrict__ tW1s, const __bf16* __restrict__ tWos,
    const __bf16* __restrict__ tW1c, const __bf16* __restrict__ tWoc,
    __bf16* __restrict__ tW1f)
{
    const int z = blockIdx.z, bx = blockIdx.x, tid = threadIdx.x;
    const __bf16* A  = (z < 9) ? tW1s + (size_t)z * 262144 : tW1c + (size_t)(z - 9) * 262144;
    const __bf16* B  = (z < 9) ? tWos + (size_t)z * 65536  : tWoc + (size_t)(z - 9) * 65536;
    __bf16* dst      = tW1f + (size_t)z * 262144;
    const int row0 = blockIdx.y * 32;

    if (bx < 4) {
        const int row = tid >> 3, kc = (tid & 7) * 8;
        bf16x8 v = *(const bf16x8*)&A[(size_t)(row0 + row) * 512 + bx * 64 + kc];
        *(bf16x8*)&dst[(size_t)(row0 + row) * 512 + bx * 64 + kc] = v;
        return;
    }

    __shared__ __bf16 As[8][32][40];
    __shared__ __bf16 Bs[8][64][40];
    const int w = tid >> 6, l = tid & 63;
    const int col0 = (bx - 4) * 64;
    const int wr = (w >> 1) * 16, wc = (w & 1) * 32;
    f32x4 acc0 = {0.f, 0.f, 0.f, 0.f};
    f32x4 acc1 = {0.f, 0.f, 0.f, 0.f};

    const int ar = tid >> 3, ac = (tid & 7) * 4;
    const int tnr = tid >> 3, tkc = (tid & 7) * 8;

    #pragma unroll
    for (int c = 0; c < 8; ++c) {
        bf16x4 av = *(const bf16x4*)&A[(size_t)(row0 + ar) * 512 + 256 + c * 32 + ac];
        *(bf16x4*)&As[c][ar][ac] = av;
        bf16x8 bv = *(const bf16x8*)&B[(size_t)(c * 32 + tnr) * 256 + col0 + tkc];
        #pragma unroll
        for (int e = 0; e < 8; ++e) Bs[c][tkc + e][tnr] = bv[e];
    }
    __syncthreads();
    #pragma unroll
    for (int c = 0; c < 8; ++c) {
        bf16x8 af  = *(const bf16x8*)&As[c][wr + (l & 15)][(l >> 4) * 8];
        bf16x8 bf0 = *(const bf16x8*)&Bs[c][wc + (l & 15)][(l >> 4) * 8];
        bf16x8 bf1 = *(const bf16x8*)&Bs[c][wc + 16 + (l & 15)][(l >> 4) * 8];
        acc0 = __builtin_amdgcn_mfma_f32_16x16x32_bf16(af, bf0, acc0, 0, 0, 0);
        acc1 = __builtin_amdgcn_mfma_f32_16x16x32_bf16(af, bf1, acc1, 0, 0, 0);
    }
    #pragma unroll
    for (int t2 = 0; t2 < 2; ++t2) {
        f32x4 a = t2 ? acc1 : acc0;
        int cc = col0 + wc + t2 * 16 + (l & 15);
        #pragma unroll
        for (int rg = 0; rg < 4; ++rg) {
            int rr = row0 + wr + (l >> 4) * 4 + rg;
            dst[(size_t)rr * 512 + 256 + cc] = f2bf(a[rg]);
        }
    }
}

// bfused[z][o] = b1[z][o] + sum_m bo[z][m] * W1[z][256+m][o]   (fp32)
__global__ __launch_bounds__(256) void bfuse_k(
    const float* __restrict__ sbo, const float* __restrict__ sfW1,
    const float* __restrict__ sfb1, const float* __restrict__ cbo,
    const float* __restrict__ cfW1, const float* __restrict__ cfb1,
    float* __restrict__ bf)
{
    const int z = blockIdx.y;
    const float* bo = (z < 9) ? sbo + z * 256 : cbo + (z - 9) * 256;
    const float* W1 = (z < 9) ? sfW1 + (size_t)z * 262144 : cfW1 + (size_t)(z - 9) * 262144;
    const float* b1 = (z < 9) ? sfb1 + z * 512 : cfb1 + (z - 9) * 512;
    const int o = blockIdx.x * 256 + threadIdx.x;
    float acc = 0.f;
    for (int m = 0; m < 256; ++m)
        acc += bo[m] * W1[(size_t)(256 + m) * 512 + o];
    bf[(size_t)z * 512 + o] = b1[o] + acc;
}

// ---------------------------------------------------------------------------
// qkv GEMM with fused RoPE + head-major bf16 store. A = bf16 xb [2048][256].
// K=256, Nn=768 (permuted: col' = t*256 + h*64 + d). Grid (12, 64).
// RoPE pair d^1 lives in the adjacent column = lane^1 -> __shfl_xor.
// ---------------------------------------------------------------------------
__global__ __launch_bounds__(256) void gemm_qkv_k(
    const __bf16* __restrict__ Ab, const __bf16* __restrict__ Bt,
    const float* __restrict__ bias,   // original order [768]
    const float* __restrict__ encc, const float* __restrict__ encs,
    __bf16* __restrict__ qh, __bf16* __restrict__ kh, __bf16* __restrict__ vh)
{
    __shared__ __bf16 As[8][32][40];
    __shared__ __bf16 Bs[8][64][40];
    const int tid = threadIdx.x;
    const int w = tid >> 6, l = tid & 63;
    const int row0 = blockIdx.y * 32, col0 = blockIdx.x * 64;
    const int wr = (w >> 1) * 16, wc = (w & 1) * 32;
    const int quad = l >> 4, l16 = l & 15;
    f32x4 acc0 = {0.f, 0.f, 0.f, 0.f};
    f32x4 acc1 = {0.f, 0.f, 0.f, 0.f};

    const int ar = tid >> 3, ac = (tid & 7) * 4;
    const int bnr = tid >> 2, bkc = (tid & 3) * 8;

    #pragma unroll
    for (int c = 0; c < 8; ++c) {
        const int k0 = c * 32;
        bf16x4 av = *(const bf16x4*)&Ab[(size_t)(row0 + ar) * 256 + k0 + ac];
        *(bf16x4*)&As[c][ar][ac] = av;
        bf16x8 bv = *(const bf16x8*)&Bt[(size_t)(col0 + bnr) * 256 + k0 + bkc];
        *(bf16x8*)&Bs[c][bnr][bkc] = bv;
    }
    __syncthreads();
    #pragma unroll
    for (int c = 0; c < 8; ++c) {
        bf16x8 af  = *(const bf16x8*)&As[c][wr + l16][quad * 8];
        bf16x8 bf0 = *(const bf16x8*)&Bs[c][wc + l16][quad * 8];
        bf16x8 bf1 = *(const bf16x8*)&Bs[c][wc + 16 + l16][quad * 8];
        acc0 = __builtin_amdgcn_mfma_f32_16x16x32_bf16(af, bf0, acc0, 0, 0, 0);
        acc1 = __builtin_amdgcn_mfma_f32_16x16x32_bf16(af, bf1, acc1, 0, 0, 0);
    }

    // ---- epilogue: bias + RoPE (q,k) + head-major bf16 store ----
    const int typ = col0 >> 8;            // 0=q 1=k 2=v
    const int hh  = (col0 & 255) >> 6;
    __bf16* dst = (typ == 0) ? qh : (typ == 1) ? kh : vh;
    #pragma unroll
    for (int t2 = 0; t2 < 2; ++t2) {
        f32x4 a = t2 ? acc1 : acc0;
        const int d = wc + t2 * 16 + l16;
        const float bvv = bias[hh * 192 + d * 3 + typ];
        float full[4], pair[4];
        #pragma unroll
        for (int rg = 0; rg < 4; ++rg) full[rg] = a[rg] + bvv;
        #pragma unroll
        for (int rg = 0; rg < 4; ++rg) pair[rg] = __shfl_xor(full[rg], 1);
        const float sgn = (d & 1) ? 1.0f : -1.0f;
        #pragma unroll
        for (int rg = 0; rg < 4; ++rg) {
            int rr = row0 + wr + quad * 4 + rg;
            float outv;
            if (typ == 2) {
                outv = full[rg];
            } else {
                float c = encc[(size_t)rr * 64 + d];
                float s = encs[(size_t)rr * 64 + d];
                outv = full[rg] * c + sgn * pair[rg] * s;
            }
            int im = rr >> 10, n = rr & 1023;
            dst[(((size_t)(im * 4 + hh)) * 1024 + n) * 64 + d] = f2bf(outv);
        }
    }
}

// ---------------------------------------------------------------------------
// Deep-staged bf16-MFMA GEMM: C = (A @ B + bias)*scale. bf16 A (ld 256,
// cols<256), OPTIONAL bf16 A1b (cols>=256, ld 256). bf16 B [Nn][K]. fp32 C.
// ---------------------------------------------------------------------------
__global__ __launch_bounds__(256) void gemm_bf_k(
    const __bf16* __restrict__ Ab, const __bf16* __restrict__ A1b,
    const __bf16* __restrict__ Bt, const float* __restrict__ bias,
    float* __restrict__ C, int K, int Nn, int ldc, float scale)
{
    __shared__ __bf16 As[8][32][40];
    __shared__ __bf16 Bs[8][64][40];
    const int tid = threadIdx.x;
    const int w = tid >> 6, l = tid & 63;
    const int row0 = blockIdx.y * 32, col0 = blockIdx.x * 64;
    const int wr = (w >> 1) * 16, wc = (w & 1) * 32;
    f32x4 acc0 = {0.f, 0.f, 0.f, 0.f};
    f32x4 acc1 = {0.f, 0.f, 0.f, 0.f};

    const int ar = tid >> 3, ac = (tid & 7) * 4;
    const int bnr = tid >> 2, bkc = (tid & 3) * 8;

    for (int p0 = 0; p0 < K; p0 += 256) {
        #pragma unroll
        for (int c = 0; c < 8; ++c) {
            const int k0 = p0 + c * 32;
            const int kk = k0 + ac;
            const __bf16* src = (A1b && kk >= 256)
                ? &A1b[(size_t)(row0 + ar) * 256 + (kk - 256)]
                : &Ab[(size_t)(row0 + ar) * 256 + kk];
            bf16x4 av = *(const bf16x4*)src;
            *(bf16x4*)&As[c][ar][ac] = av;
            bf16x8 bv = *(const bf16x8*)&Bt[(size_t)(col0 + bnr) * K + k0 + bkc];
            *(bf16x8*)&Bs[c][bnr][bkc] = bv;
        }
        __syncthreads();
        #pragma unroll
        for (int c = 0; c < 8; ++c) {
            bf16x8 af  = *(const bf16x8*)&As[c][wr + (l & 15)][(l >> 4) * 8];
            bf16x8 bf0 = *(const bf16x8*)&Bs[c][wc + (l & 15)][(l >> 4) * 8];
            bf16x8 bf1 = *(const bf16x8*)&Bs[c][wc + 16 + (l & 15)][(l >> 4) * 8];
            acc0 = __builtin_amdgcn_mfma_f32_16x16x32_bf16(af, bf0, acc0, 0, 0, 0);
            acc1 = __builtin_amdgcn_mfma_f32_16x16x32_bf16(af, bf1, acc1, 0, 0, 0);
        }
        __syncthreads();
    }

    #pragma unroll
    for (int t2 = 0; t2 < 2; ++t2) {
        f32x4 a = t2 ? acc1 : acc0;
        int cc = col0 + wc + t2 * 16 + (l & 15);
        float bvv = bias ? bias[cc] : 0.0f;
        #pragma unroll
        for (int rg = 0; rg < 4; ++rg) {
            int rr = row0 + wr + (l >> 4) * 4 + rg;
            C[(size_t)rr * ldc + cc] = (a[rg] + bvv) * scale;
        }
    }
}

// ---------------------------------------------------------------------------
// Head projection GEMM with bf16 output: Cb = f2bf((A @ B + bias)*scale).
// bf16 A [M][256], bf16 B [Nn][256], K=256 single phase. Grid (4, 64).
// ---------------------------------------------------------------------------
__global__ __launch_bounds__(256) void gemm_bfb_k(
    const __bf16* __restrict__ Ab, const __bf16* __restrict__ Bt,
    const float* __restrict__ bias, __bf16* __restrict__ Cb, float scale)
{
    __shared__ __bf16 As[8][32][40];
    __shared__ __bf16 Bs[8][64][40];
    const int tid = threadIdx.x;
    const int w = tid >> 6, l = tid & 63;
    const int row0 = blockIdx.y * 32, col0 = blockIdx.x * 64;
    const int wr = (w >> 1) * 16, wc = (w & 1) * 32;
    f32x4 acc0 = {0.f, 0.f, 0.f, 0.f};
    f32x4 acc1 = {0.f, 0.f, 0.f, 0.f};

    const int ar = tid >> 3, ac = (tid & 7) * 4;
    const int bnr = tid >> 2, bkc = (tid & 3) * 8;

    #pragma unroll
    for (int c = 0; c < 8; ++c) {
        const int k0 = c * 32;
        bf16x4 av = *(const bf16x4*)&Ab[(size_t)(row0 + ar) * 256 + k0 + ac];
        *(bf16x4*)&As[c][ar][ac] = av;
        bf16x8 bv = *(const bf16x8*)&Bt[(size_t)(col0 + bnr) * 256 + k0 + bkc];
        *(bf16x8*)&Bs[c][bnr][bkc] = bv;
    }
    __syncthreads();
    #pragma unroll
    for (int c = 0; c < 8; ++c) {
        bf16x8 af  = *(const bf16x8*)&As[c][wr + (l & 15)][(l >> 4) * 8];
        bf16x8 bf0 = *(const bf16x8*)&Bs[c][wc + (l & 15)][(l >> 4) * 8];
        bf16x8 bf1 = *(const bf16x8*)&Bs[c][wc + 16 + (l & 15)][(l >> 4) * 8];
        acc0 = __builtin_amdgcn_mfma_f32_16x16x32_bf16(af, bf0, acc0, 0, 0, 0);
        acc1 = __builtin_amdgcn_mfma_f32_16x16x32_bf16(af, bf1, acc1, 0, 0, 0);
    }

    #pragma unroll
    for (int t2 = 0; t2 < 2; ++t2) {
        f32x4 a = t2 ? acc1 : acc0;
        int cc = col0 + wc + t2 * 16 + (l & 15);
        float bvv = bias[cc];
        #pragma unroll
        for (int rg = 0; rg < 4; ++rg) {
            int rr = row0 + wr + (l >> 4) * 4 + rg;
            Cb[(size_t)rr * 256 + cc] = f2bf((a[rg] + bvv) * scale);
        }
    }
}

// ---------------------------------------------------------------------------
// Fused LN(512)+GELU+FFN2: one block = 16 rows x ALL 256 output cols.
// Grid 128, 256 threads (4 waves; wave w owns cols w*64..w*64+64).
// Phase A: thread (r=tid>>4, sub=tid&15) reads pre[row0+r][sub*32..+32) into
//   regs; LN stats via 16-lane shfl reduce (block-local, no redundancy).
// Phase B: GELU applied ONCE per element; h stored to LDS directly in the
//   MFMA-A layout hAs[p][c][r][j] (k = sub*32+j => p=sub>>3, c=sub&7).
// Phase C: GEMM K=512: A-frags from LDS, B-frags (W2 [256][512], L2-resident)
//   read DIRECT from global (no LDS staging; B tile for 256 cols would be
//   128 KB). Epilogue: +bias +residual -> x, xb.
// ---------------------------------------------------------------------------
__global__ __launch_bounds__(256) void ffn2f_k(
    const float* __restrict__ pre, const float* __restrict__ g,
    const float* __restrict__ beta, const __bf16* __restrict__ Bt,
    const float* __restrict__ bias, float* __restrict__ x,
    __bf16* __restrict__ xb)
{
    __shared__ __bf16 hAs[2][8][16][40];
    const int tid = threadIdx.x;
    const int r = tid >> 4, sub = tid & 15;
    const int row0 = blockIdx.x * 16;

    // ---- Phase A: load 32 elems, LN stats over the 16-lane row group ----
    float v[32];
    const float* pr = pre + (size_t)(row0 + r) * 512 + sub * 32;
    float s = 0.f;
    #pragma unroll
    for (int j4 = 0; j4 < 8; ++j4) {
        float4 t = *(const float4*)&pr[j4 * 4];
        v[j4 * 4 + 0] = t.x; v[j4 * 4 + 1] = t.y;
        v[j4 * 4 + 2] = t.z; v[j4 * 4 + 3] = t.w;
        s += t.x + t.y + t.z + t.w;
    }
    #pragma unroll
    for (int ofs = 1; ofs < 16; ofs <<= 1) s += __shfl_xor(s, ofs);
    const float mu = s * (1.0f / 512.0f);
    float ss = 0.f;
    #pragma unroll
    for (int j = 0; j < 32; ++j) { float d = v[j] - mu; ss += d * d; }
    #pragma unroll
    for (int ofs = 1; ofs < 16; ofs <<= 1) ss += __shfl_xor(ss, ofs);
    const float rstd = rsqrtf(ss * (1.0f / 512.0f) + 1e-5f);

    // ---- Phase B: GELU once, store h into LDS in MFMA-A layout ----
    const int p = sub >> 3, c = sub & 7;
    const float IS2 = 0.70710678118654752f;
    bf16x8 hb8[4];
    #pragma unroll
    for (int j4 = 0; j4 < 8; ++j4) {
        float4 gg = *(const float4*)&g[sub * 32 + j4 * 4];
        float4 bb = *(const float4*)&beta[sub * 32 + j4 * 4];
        float y;
        y = (v[j4*4+0] - mu) * rstd * gg.x + bb.x;
        hb8[j4 >> 1][(j4 & 1) * 4 + 0] = f2bf(0.5f * y * (1.0f + erff(y * IS2)));
        y = (v[j4*4+1] - mu) * rstd * gg.y + bb.y;
        hb8[j4 >> 1][(j4 & 1) * 4 + 1] = f2bf(0.5f * y * (1.0f + erff(y * IS2)));
        y = (v[j4*4+2] - mu) * rstd * gg.z + bb.z;
        hb8[j4 >> 1][(j4 & 1) * 4 + 2] = f2bf(0.5f * y * (1.0f + erff(y * IS2)));
        y = (v[j4*4+3] - mu) * rstd * gg.w + bb.w;
        hb8[j4 >> 1][(j4 & 1) * 4 + 3] = f2bf(0.5f * y * (1.0f + erff(y * IS2)));
    }
    #pragma unroll
    for (int j8 = 0; j8 < 4; ++j8)
        *(bf16x8*)&hAs[p][c][r][j8 * 8] = hb8[j8];
    __syncthreads();

    // ---- Phase C: GEMM 16 x 256, K=512 ----
    const int w = tid >> 6, l = tid & 63;
    const int quad = l >> 4, l16 = l & 15;
    f32x4 acc0 = {0.f, 0.f, 0.f, 0.f};
    f32x4 acc1 = {0.f, 0.f, 0.f, 0.f};
    f32x4 acc2 = {0.f, 0.f, 0.f, 0.f};
    f32x4 acc3 = {0.f, 0.f, 0.f, 0.f};
    const size_t bcol = (size_t)(w * 64 + l16) * 512;
    #pragma unroll
    for (int p2 = 0; p2 < 2; ++p2) {
        #pragma unroll
        for (int c2 = 0; c2 < 8; ++c2) {
            bf16x8 af = *(const bf16x8*)&hAs[p2][c2][l16][quad * 8];
            const size_t kofs = p2 * 256 + c2 * 32 + quad * 8;
            bf16x8 b0 = *(const bf16x8*)&Bt[bcol + kofs];
            bf16x8 b1 = *(const bf16x8*)&Bt[bcol + 16 * 512 + kofs];
            bf16x8 b2 = *(const bf16x8*)&Bt[bcol + 32 * 512 + kofs];
            bf16x8 b3 = *(const bf16x8*)&Bt[bcol + 48 * 512 + kofs];
            acc0 = __builtin_amdgcn_mfma_f32_16x16x32_bf16(af, b0, acc0, 0, 0, 0);
            acc1 = __builtin_amdgcn_mfma_f32_16x16x32_bf16(af, b1, acc1, 0, 0, 0);
            acc2 = __builtin_amdgcn_mfma_f32_16x16x32_bf16(af, b2, acc2, 0, 0, 0);
            acc3 = __builtin_amdgcn_mfma_f32_16x16x32_bf16(af, b3, acc3, 0, 0, 0);
        }
    }

    // ---- epilogue: bias + residual -> x, xb ----
    #pragma unroll
    for (int f = 0; f < 4; ++f) {
        f32x4 a = (f == 0) ? acc0 : (f == 1) ? acc1 : (f == 2) ? acc2 : acc3;
        int cc = w * 64 + f * 16 + l16;
        float bvv = bias[cc];
        #pragma unroll
        for (int rg = 0; rg < 4; ++rg) {
            int rr = row0 + quad * 4 + rg;
            float outv = a[rg] + bvv + x[(size_t)rr * 256 + cc];
            x[(size_t)rr * 256 + cc]  = outv;
            xb[(size_t)rr * 256 + cc] = f2bf(outv);
        }
    }
}

// ---------------------------------------------------------------------------
// Cross qk+v fused GEMM (deep-staged, K=256): grid (8, 64). bx<4 -> Wq, else Wv.
// A = bf16 xb.
// ---------------------------------------------------------------------------
__global__ __launch_bounds__(256) void gemm_hm2_k(
    const __bf16* __restrict__ Ab, const __bf16* __restrict__ Btq,
    const float* __restrict__ bq, const __bf16* __restrict__ Btv,
    const float* __restrict__ bv, __bf16* __restrict__ outq,
    __bf16* __restrict__ outv, float scaleq)
{
    const int bx = blockIdx.x;
    const __bf16* Bt  = (bx < 4) ? Btq : Btv;
    const float* bias = (bx < 4) ? bq : bv;
    __bf16* C         = (bx < 4) ? outq : outv;
    const float scale = (bx < 4) ? scaleq : 1.0f;

    __shared__ __bf16 As[8][32][40];
    __shared__ __bf16 Bs[8][64][40];
    const int tid = threadIdx.x;
    const int w = tid >> 6, l = tid & 63;
    const int row0 = blockIdx.y * 32, col0 = (bx & 3) * 64;
    const int wr = (w >> 1) * 16, wc = (w & 1) * 32;
    f32x4 acc0 = {0.f, 0.f, 0.f, 0.f};
    f32x4 acc1 = {0.f, 0.f, 0.f, 0.f};

    const int ar = tid >> 3, ac = (tid & 7) * 4;
    const int bnr = tid >> 2, bkc = (tid & 3) * 8;

    #pragma unroll
    for (int c = 0; c < 8; ++c) {
        const int k0 = c * 32;
        bf16x4 av = *(const bf16x4*)&Ab[(size_t)(row0 + ar) * 256 + k0 + ac];
        *(bf16x4*)&As[c][ar][ac] = av;
        bf16x8 bv8 = *(const bf16x8*)&Bt[(size_t)(col0 + bnr) * 256 + k0 + bkc];
        *(bf16x8*)&Bs[c][bnr][bkc] = bv8;
    }
    __syncthreads();
    #pragma unroll
    for (int c = 0; c < 8; ++c) {
        bf16x8 af  = *(const bf16x8*)&As[c][wr + (l & 15)][(l >> 4) * 8];
        bf16x8 bf0 = *(const bf16x8*)&Bs[c][wc + (l & 15)][(l >> 4) * 8];
        bf16x8 bf1 = *(const bf16x8*)&Bs[c][wc + 16 + (l & 15)][(l >> 4) * 8];
        acc0 = __builtin_amdgcn_mfma_f32_16x16x32_bf16(af, bf0, acc0, 0, 0, 0);
        acc1 = __builtin_amdgcn_mfma_f32_16x16x32_bf16(af, bf1, acc1, 0, 0, 0);
    }

    #pragma unroll
    for (int t2 = 0; t2 < 2; ++t2) {
        f32x4 a = t2 ? acc1 : acc0;
        int cc = col0 + wc + t2 * 16 + (l & 15);
        float bvv = bias ? bias[cc] : 0.0f;
        int h = cc >> 6, d = cc & 63;
        #pragma unroll
        for (int rg = 0; rg < 4; ++rg) {
            int rr = row0 + wr + (l >> 4) * 4 + rg;
            int im = rr >> 10, n = rr & 1023;
            C[(((size_t)(im * 4 + h)) * 1024 + n) * 64 + d] = f2bf((a[rg] + bvv) * scale);
        }
    }
}

// ---------------------------------------------------------------------------
// sim = A @ B^T, bf16 A,B (mdb halves), K=256 single phase, fp32 C.
// Grid (16, 32).
// ---------------------------------------------------------------------------
__global__ __launch_bounds__(256) void gemm_bt_k(
    const __bf16* __restrict__ Ab, const __bf16* __restrict__ Bb,
    float* __restrict__ C, int Nn)
{
    __shared__ __bf16 As[8][32][40];
    __shared__ __bf16 Bs[8][64][40];
    const int tid = threadIdx.x;
    const int w = tid >> 6, l = tid & 63;
    const int row0 = blockIdx.y * 32, col0 = blockIdx.x * 64;
    const int wr = (w >> 1) * 16, wc = (w & 1) * 32;
    f32x4 acc0 = {0.f, 0.f, 0.f, 0.f};
    f32x4 acc1 = {0.f, 0.f, 0.f, 0.f};

    const int ar = tid >> 3, ac = (tid & 7) * 4;
    const int bnr = tid >> 2, bkc = (tid & 3) * 8;

    #pragma unroll
    for (int c = 0; c < 8; ++c) {
        const int k0 = c * 32;
        bf16x4 av = *(const bf16x4*)&Ab[(size_t)(row0 + ar) * 256 + k0 + ac];
        *(bf16x4*)&As[c][ar][ac] = av;
        bf16x8 bv = *(const bf16x8*)&Bb[(size_t)(col0 + bnr) * 256 + k0 + bkc];
        *(bf16x8*)&Bs[c][bnr][bkc] = bv;
    }
    __syncthreads();
    #pragma unroll
    for (int c = 0; c < 8; ++c) {
        bf16x8 af  = *(const bf16x8*)&As[c][wr + (l & 15)][(l >> 4) * 8];
        bf16x8 bf0 = *(const bf16x8*)&Bs[c][wc + (l & 15)][(l >> 4) * 8];
        bf16x8 bf1 = *(const bf16x8*)&Bs[c][wc + 16 + (l & 15)][(l >> 4) * 8];
        acc0 = __builtin_amdgcn_mfma_f32_16x16x32_bf16(af, bf0, acc0, 0, 0, 0);
        acc1 = __builtin_amdgcn_mfma_f32_16x16x32_bf16(af, bf1, acc1, 0, 0, 0);
    }

    #pragma unroll
    for (int t2 = 0; t2 < 2; ++t2) {
        f32x4 a = t2 ? acc1 : acc0;
        int cc = col0 + wc + t2 * 16 + (l & 15);
        #pragma unroll
        for (int rg = 0; rg < 4; ++rg) {
            int rr = row0 + wr + (l >> 4) * 4 + rg;
            C[(size_t)rr * Nn + cc] = a[rg];
        }
    }
}

// ---------------------------------------------------------------------------
// Fused init: desc copies (fp32 + bf16 mirror) + posenc. Grid 2304 x 256.
// ---------------------------------------------------------------------------
__global__ __launch_bounds__(256) void init_k(
    const float* __restrict__ desc0, const float* __restrict__ desc1,
    const float* __restrict__ kpts0, const float* __restrict__ kpts1,
    const float* __restrict__ Wr, float* __restrict__ x,
    __bf16* __restrict__ xb,
    float* __restrict__ encc, float* __restrict__ encs)
{
    int idx = blockIdx.x * 256 + threadIdx.x;
    if (idx < 524288) {
        float v = (idx < 262144) ? desc0[idx] : desc1[idx - 262144];
        x[idx]  = v;
        xb[idx] = f2bf(v);
    } else {
        int p = idx - 524288;
        int im = p >> 15, q = p & 32767;
        int i = q >> 5, f = q & 31;
        const float* kp = im ? kpts1 : kpts0;
        float* ec = encc + im * 65536;
        float* es = encs + im * 65536;
        float pr = kp[i * 2] * Wr[f] + kp[i * 2 + 1] * Wr[32 + f];
        float c = cosf(pr), s = sinf(pr);
        ec[i * 64 + 2 * f] = c; ec[i * 64 + 2 * f + 1] = c;
        es[i * 64 + 2 * f] = s; es[i * 64 + 2 * f + 1] = s;
    }
}

// ---------------------------------------------------------------------------
// Attention v6: flash-style bf16 MFMA with K/V register prefetch pipelining.
// Output msg written bf16 [2048][256].
// ---------------------------------------------------------------------------
__global__ __launch_bounds__(256) void attn_k(
    const __bf16* __restrict__ Qg, const __bf16* __restrict__ Kg,
    const __bf16* __restrict__ Vg, __bf16* __restrict__ out,
    float scale, int cross)
{
    const int qt = blockIdx.x, hv = blockIdx.y;
    const int kvh = cross ? (hv ^ 4) : hv;
    const int tid = threadIdx.x;
    const int w = tid >> 6, lane = tid & 63;
    const int quad = lane >> 4, l16 = lane & 15;
    const int n0 = qt * 16;

    __shared__ __align__(16) char smem[44032];
    char* base = smem + w * 11008;
    __bf16* kb  = (__bf16*)(base);          // 32 x 72
    __bf16* vtb = (__bf16*)(base + 4608);   // 64 x 40
    __bf16* ptb = (__bf16*)(base + 9728);   // 16 x 40

    bf16x8 qf[2];
    {
        const bf16x8* Qp = (const bf16x8*)(Qg + (((size_t)hv * 1024) + n0 + l16) * 64);
        qf[0] = Qp[quad];
        qf[1] = Qp[4 + quad];
    }

    const __bf16* Kbase = Kg + (size_t)kvh * 1024 * 64;
    const __bf16* Vbase = Vg + (size_t)kvh * 1024 * 64;

    float m[4] = {-1e30f, -1e30f, -1e30f, -1e30f};
    float lsum[4] = {0.f, 0.f, 0.f, 0.f};
    f32x4 o[4] = {{0,0,0,0},{0,0,0,0},{0,0,0,0},{0,0,0,0}};

    const int kj = lane >> 1, kd = (lane & 1) * 32;
    const int vjp = lane & 15, vd0 = (lane >> 4) * 16;

    bf16x8 kr[4];
    uint4  vr[4];
    {
        const int j0 = w * 256;
        const bf16x8* kp = (const bf16x8*)(Kbase + (size_t)(j0 + kj) * 64 + kd);
        kr[0] = kp[0]; kr[1] = kp[1]; kr[2] = kp[2]; kr[3] = kp[3];
        const uint4* va = (const uint4*)(Vbase + (size_t)(j0 + 2 * vjp) * 64 + vd0);
        const uint4* vb = (const uint4*)(Vbase + (size_t)(j0 + 2 * vjp + 1) * 64 + vd0);
        vr[0] = va[0]; vr[1] = va[1]; vr[2] = vb[0]; vr[3] = vb[1];
    }

    for (int t = 0; t < 8; ++t) {
        {
            __bf16* krow = kb + kj * 72 + kd;
            *(bf16x8*)(krow)      = kr[0];
            *(bf16x8*)(krow + 8)  = kr[1];
            *(bf16x8*)(krow + 16) = kr[2];
            *(bf16x8*)(krow + 24) = kr[3];
            #pragma unroll
            for (int g = 0; g < 2; ++g) {
                uint4 ua = vr[g], ub = vr[2 + g];
                unsigned au[4] = {ua.x, ua.y, ua.z, ua.w};
                unsigned bu[4] = {ub.x, ub.y, ub.z, ub.w};
                #pragma unroll
                for (int e = 0; e < 4; ++e) {
                    int i = g * 8 + e * 2;
                    unsigned pk0 = ((bu[e] & 0xFFFFu) << 16) | (au[e] & 0xFFFFu);
                    unsigned pk1 = (bu[e] & 0xFFFF0000u) | (au[e] >> 16);
                    *(unsigned*)((char*)vtb + ((vd0 + i) * 40 + 2 * vjp) * 2)     = pk0;
                    *(unsigned*)((char*)vtb + ((vd0 + i + 1) * 40 + 2 * vjp) * 2) = pk1;
                }
            }
        }
        if (t < 7) {
            const int j1 = w * 256 + (t + 1) * 32;
            const bf16x8* kp = (const bf16x8*)(Kbase + (size_t)(j1 + kj) * 64 + kd);
            kr[0] = kp[0]; kr[1] = kp[1]; kr[2] = kp[2]; kr[3] = kp[3];
            const uint4* va = (const uint4*)(Vbase + (size_t)(j1 + 2 * vjp) * 64 + vd0);
            const uint4* vb = (const uint4*)(Vbase + (size_t)(j1 + 2 * vjp + 1) * 64 + vd0);
            vr[0] = va[0]; vr[1] = va[1]; vr[2] = vb[0]; vr[3] = vb[1];
        }

        f32x4 s0 = {0,0,0,0}, s1 = {0,0,0,0};
        #pragma unroll
        for (int kt = 0; kt < 2; ++kt) {
            bf16x8 k0 = *(const bf16x8*)(kb + (0 * 16 + l16) * 72 + kt * 32 + quad * 8);
            bf16x8 k1 = *(const bf16x8*)(kb + (1 * 16 + l16) * 72 + kt * 32 + quad * 8);
            s0 = __builtin_amdgcn_mfma_f32_16x16x32_bf16(qf[kt], k0, s0, 0, 0, 0);
            s1 = __builtin_amdgcn_mfma_f32_16x16x32_bf16(qf[kt], k1, s1, 0, 0, 0);
        }

        float rm[4], p0[4], p1[4], rs[4];
        #pragma unroll
        for (int r = 0; r < 4; ++r) {
            s0[r] *= scale; s1[r] *= scale;
            rm[r] = fmaxf(s0[r], s1[r]);
        }
        #pragma unroll
        for (int ofs = 1; ofs < 16; ofs <<= 1)
            #pragma unroll
            for (int r = 0; r < 4; ++r)
                rm[r] = fmaxf(rm[r], __shfl_xor(rm[r], ofs));
        #pragma unroll
        for (int r = 0; r < 4; ++r) {
            float mn = fmaxf(m[r], rm[r]);
            float alpha = __expf(m[r] - mn);
            m[r] = mn;
            p0[r] = __expf(s0[r] - mn);
            p1[r] = __expf(s1[r] - mn);
            rs[r] = p0[r] + p1[r];
            lsum[r] *= alpha;
            #pragma unroll
            for (int dt = 0; dt < 4; ++dt) o[dt][r] *= alpha;
        }
        #pragma unroll
        for (int ofs = 1; ofs < 16; ofs <<= 1)
            #pragma unroll
            for (int r = 0; r < 4; ++r)
                rs[r] += __shfl_xor(rs[r], ofs);
        #pragma unroll
        for (int r = 0; r < 4; ++r) lsum[r] += rs[r];

        #pragma unroll
        for (int r = 0; r < 4; ++r) {
            ptb[(quad * 4 + r) * 40 + l16]      = f2bf(p0[r]);
            ptb[(quad * 4 + r) * 40 + 16 + l16] = f2bf(p1[r]);
        }
        bf16x8 pf = *(const bf16x8*)(ptb + l16 * 40 + quad * 8);
        #pragma unroll
        for (int dt = 0; dt < 4; ++dt) {
            bf16x8 vf = *(const bf16x8*)(vtb + (dt * 16 + l16) * 40 + quad * 8);
            o[dt] = __builtin_amdgcn_mfma_f32_16x16x32_bf16(pf, vf, o[dt], 0, 0, 0);
        }
    }

    __syncthreads();
    float* Om = (float*)smem;          // [64][64] : row = w*16 + q
    float* mm = Om + 4096;             // [64]
    float* lm = mm + 64;               // [64]
    #pragma unroll
    for (int dt = 0; dt < 4; ++dt)
        #pragma unroll
        for (int r = 0; r < 4; ++r)
            Om[(w * 16 + quad * 4 + r) * 64 + dt * 16 + l16] = o[dt][r];
    if (l16 == 0) {
        #pragma unroll
        for (int r = 0; r < 4; ++r) {
            mm[w * 16 + quad * 4 + r] = m[r];
            lm[w * 16 + quad * 4 + r] = lsum[r];
        }
    }
    __syncthreads();

    const int q = tid >> 4, dg = tid & 15;
    float M = -1e30f;
    #pragma unroll
    for (int w2 = 0; w2 < 4; ++w2) M = fmaxf(M, mm[w2 * 16 + q]);
    float L = 0.f;
    float4 acc = {0.f, 0.f, 0.f, 0.f};
    #pragma unroll
    for (int w2 = 0; w2 < 4; ++w2) {
        float e = __expf(mm[w2 * 16 + q] - M);
        L += e * lm[w2 * 16 + q];
        float4 ov = *(const float4*)&Om[(w2 * 16 + q) * 64 + dg * 4];
        acc.x += e * ov.x; acc.y += e * ov.y; acc.z += e * ov.z; acc.w += e * ov.w;
    }
    float inv = 1.0f / L;
    bf16x4 ob;
    ob[0] = f2bf(acc.x * inv); ob[1] = f2bf(acc.y * inv);
    ob[2] = f2bf(acc.z * inv); ob[3] = f2bf(acc.w * inv);
    int row = (hv >> 2) * 1024 + n0 + q;
    *(bf16x4*)&out[(size_t)row * 256 + (hv & 3) * 64 + dg * 4] = ob;
}

// z = x @ Wz + bz : wave-per-row, float4 + shfl reduce. Grid 512.
__global__ __launch_bounds__(256) void z_k(
    const float* __restrict__ x, const float* __restrict__ Wz,
    const float* __restrict__ bz, float* __restrict__ z)
{
    int row = blockIdx.x * 4 + (threadIdx.x >> 6);
    int lane = threadIdx.x & 63;
    float4 v  = *(const float4*)&x[(size_t)row * 256 + lane * 4];
    float4 wv = *(const float4*)&Wz[lane * 4];
    float s = v.x * wv.x + v.y * wv.y + v.z * wv.z + v.w * wv.w;
    #pragma unroll
    for (int ofs = 1; ofs < 64; ofs <<= 1) s += __shfl_xor(s, ofs);
    if (lane == 0) z[row] = s + bz[0];
}

// Row lse (blocks 0..1023) and col lse (blocks 1024..2047) in one dispatch.
__global__ __launch_bounds__(256) void lse_k(
    const float* __restrict__ sim, float* __restrict__ rls,
    float* __restrict__ cls)
{
    const int b = blockIdx.x, t = threadIdx.x;
    const int isCol = b >> 10, rc = b & 1023;
    const size_t base = isCol ? (size_t)rc : (size_t)rc * 1024;
    const size_t stride = isCol ? 1024 : 1;
    __shared__ float red[256];
    float mx = -1e30f;
    for (int j = t; j < NTOK; j += 256) mx = fmaxf(mx, sim[base + stride * j]);
    red[t] = mx; __syncthreads();
    for (int s = 128; s > 0; s >>= 1) {
        if (t < s) red[t] = fmaxf(red[t], red[t + s]);
        __syncthreads();
    }
    mx = red[0]; __syncthreads();
    float sum = 0.0f;
    for (int j = t; j < NTOK; j += 256) sum += expf(sim[base + stride * j] - mx);
    red[t] = sum; __syncthreads();
    for (int s = 128; s > 0; s >>= 1) {
        if (t < s) red[t] += red[t + s];
        __syncthreads();
    }
    if (t == 0) (isCol ? cls : rls)[rc] = mx + logf(red[0]);
}

__global__ __launch_bounds__(256) void assemble_k(
    const float* __restrict__ sim, const float* __restrict__ rls,
    const float* __restrict__ cls, const float* __restrict__ z0,
    const float* __restrict__ z1, float* __restrict__ out)
{
    int idx = blockIdx.x * 256 + threadIdx.x;
    const int W = NTOK + 1;
    if (idx >= W * W) return;
    int i = idx / W, j = idx % W;
    float v;
    if (i < NTOK && j < NTOK) {
        v = 2.0f * sim[(size_t)i * NTOK + j] - rls[i] - cls[j] + logsigf(z0[i]) + logsigf(z1[j]);
    } else if (i < NTOK) {
        v = logsigf(-z0[i]);
    } else if (j < NTOK) {
        v = logsigf(-z1[j]);
    } else {
        v = 0.0f;
    }
    out[idx] = v;
}

// ---------------------------------------------------------------------------
extern "C" void kernel_launch(void* const* d_in, const int* in_sizes, int n_in,
                              void* d_out, int out_size, void* d_ws, size_t ws_size,
                              hipStream_t stream)
{
    const float* desc0 = (const float*)d_in[0];
    const float* desc1 = (const float*)d_in[1];
    const float* kpts0 = (const float*)d_in[2];
    const float* kpts1 = (const float*)d_in[3];
    const float* Wr    = (const float*)d_in[4];
    const float* sWqkv = (const float*)d_in[5];
    const float* sbqkv = (const float*)d_in[6];
    const float* sWo   = (const float*)d_in[7];
    const float* sbo   = (const float*)d_in[8];
    const float* sfW1  = (const float*)d_in[9];
    const float* sfb1  = (const float*)d_in[10];
    const float* sfg   = (const float*)d_in[11];
    const float* sfbt  = (const float*)d_in[12];
    const float* sfW2  = (const float*)d_in[13];
    const float* sfb2  = (const float*)d_in[14];
    const float* cWqk  = (const float*)d_in[15];
    const float* cbqk  = (const float*)d_in[16];
    const float* cWv   = (const float*)d_in[17];
    const float* cbv   = (const float*)d_in[18];
    const float* cWo   = (const float*)d_in[19];
    const float* cbo   = (const float*)d_in[20];
    const float* cfW1  = (const float*)d_in[21];
    const float* cfb1  = (const float*)d_in[22];
    const float* cfg   = (const float*)d_in[23];
    const float* cfbt  = (const float*)d_in[24];
    const float* cfW2  = (const float*)d_in[25];
    const float* cfb2  = (const float*)d_in[26];
    const float* mWp   = (const float*)d_in[27];
    const float* mbp   = (const float*)d_in[28];
    const float* mWz   = (const float*)d_in[29];
    const float* mbz   = (const float*)d_in[30];

    float* ws = (float*)d_ws;
    // Layout (float units):
    float*  x    = ws;                      // 524288  [2048][256] fp32
    float*  encc = ws + 524288;             // 131072  [2048][64]
    float*  encs = ws + 655360;             // 131072
    float*  pre  = ws + 786432;             // 1048576 [2048][512] fp32
    __bf16* qh   = (__bf16*)(ws + 2359296); // 262144 fl
    __bf16* kh   = (__bf16*)(ws + 2621440); // 262144 fl
    __bf16* vh   = (__bf16*)(ws + 2883584); // 262144 fl
    __bf16* msgb = (__bf16*)(ws + 3145728); // 131072 fl = [2048][256] bf16
    float*  zb   = ws + 3276800;            // 2048
    float*  rlsb = ws + 3278848;            // 1024
    float*  clsb = ws + 3279872;            // 1024
    float*  sim  = pre;                     // 1048576 (assignment; pre dead)
    __bf16* mdb  = (__bf16*)(ws + 1835008); // [2048][256] bf16 (assignment)

    // bf16 pre-transposed weights [N][K]
    __bf16* wb    = (__bf16*)(ws + 3280896);
    __bf16* tWqkv = wb;                     // 9*768*256 (rows permuted t*256+h*64+d)
    __bf16* tWo   = tWqkv + 1769472;
    __bf16* tW1   = tWo   + 589824;
    __bf16* tW2   = tW1   + 2359296;
    __bf16* tcQk  = tW2   + 1179648;
    __bf16* tcV   = tcQk  + 589824;
    __bf16* tcWo  = tcV   + 589824;
    __bf16* tcW1  = tcWo  + 589824;
    __bf16* tcW2  = tcW1  + 2359296;
    __bf16* tmWp  = tcW2  + 1179648;        // 65536   (wb total 11272192 bf16)
    __bf16* tW1f  = (__bf16*)(ws + 8916992);   // 4718592 bf16 = 2359296 fl
    float*  bfb   = ws + 11276288;             // 18*512 = 9216 fl
    __bf16* xb    = (__bf16*)(ws + 11285504);  // 524288 bf16 = 262144 fl (total ~46.2 MB)

    // ---- one-time: transposes (+qkv perm), weight fusion, bias fusion ----
    wtrans_all_k<<<dim3(24, 16, 82), 256, 0, stream>>>(
        sWqkv, sWo, sfW1, sfW2, cWqk, cWv, cWo, cfW1, cfW2, mWp, wb);
    wfuse_k<<<dim3(8, 16, 18), 256, 0, stream>>>(tW1, tWo, tcW1, tcWo, tW1f);
    bfuse_k<<<dim3(2, 18), 256, 0, stream>>>(sbo, sfW1, sfb1, cbo, cfW1, cfb1, bfb);

    const float SELF_SCALE  = 0.125f;               // DH^-0.5
    const float CROSS_SCALE = 0.35355339059327373f; // DH^-0.25

    init_k<<<2304, 256, 0, stream>>>(desc0, desc1, kpts0, kpts1, Wr, x, xb, encc, encs);

    for (int l = 0; l < NL; ++l) {
        // ---- self block ----
        gemm_qkv_k<<<dim3(12, 64), 256, 0, stream>>>(
            xb, tWqkv + (size_t)l * 196608, sbqkv + (size_t)l * 768,
            encc, encs, qh, kh, vh);
        attn_k<<<dim3(64, 8), 256, 0, stream>>>(qh, kh, vh, msgb, SELF_SCALE, 0);
        gemm_bf_k<<<dim3(8, 64), 256, 0, stream>>>(
            xb, msgb, tW1f + (size_t)l * 262144, bfb + (size_t)l * 512,
            pre, 512, 512, 512, 1.0f);
        ffn2f_k<<<128, 256, 0, stream>>>(
            pre, sfg + (size_t)l * 512, sfbt + (size_t)l * 512,
            tW2 + (size_t)l * 131072, sfb2 + (size_t)l * 256, x, xb);

        // ---- cross block ----
        gemm_hm2_k<<<dim3(8, 64), 256, 0, stream>>>(
            xb, tcQk + (size_t)l * 65536, cbqk + (size_t)l * 256,
            tcV + (size_t)l * 65536, cbv + (size_t)l * 256,
            qh, vh, CROSS_SCALE);
        attn_k<<<dim3(64, 8), 256, 0, stream>>>(qh, qh, vh, msgb, 1.0f, 1);
        gemm_bf_k<<<dim3(8, 64), 256, 0, stream>>>(
            xb, msgb, tW1f + (size_t)(9 + l) * 262144, bfb + (size_t)(9 + l) * 512,
            pre, 512, 512, 512, 1.0f);
        ffn2f_k<<<128, 256, 0, stream>>>(
            pre, cfg + (size_t)l * 512, cfbt + (size_t)l * 512,
            tcW2 + (size_t)l * 131072, cfb2 + (size_t)l * 256, x, xb);
    }

    // ---- assignment head ----
    const float MD_SCALE = 0.25f; // D^-0.25
    gemm_bfb_k<<<dim3(4, 64), 256, 0, stream>>>(xb, tmWp, mbp, mdb, MD_SCALE);
    z_k<<<512, 256, 0, stream>>>(x, mWz, mbz, zb);
    gemm_bt_k<<<dim3(16, 32), 256, 0, stream>>>(mdb, mdb + 1024 * 256, sim, 1024);
    lse_k<<<2048, 256, 0, stream>>>(sim, rlsb, clsb);
    const int W = NTOK + 1;
    assemble_k<<<(W * W + 255) / 256, 256, 0, stream>>>(sim, rlsb, clsb, zb, zb + 1024, (float*)d_out);
}

// Round 8
// 968.489 us; speedup vs baseline: 1.1462x; 1.1462x over previous
//
#include <hip/hip_runtime.h>
#include <cmath>

// LightGlue forward. All GEMMs + attention in bf16 MFMA. Q/K/V written bf16
// head-major directly by the qkv GEMM epilogue (RoPE fused via lane-shuffle).
// msg stored bf16. Wo folded into W1 (Wf = Wo@W1b). Residual stream: fp32 x
// + bf16 mirror xb. LN+GELU+FFN2 fused (ffn3_k): proven gemm_bfa structure
// (LDS-staged B, 64-col tiles) with A from on-the-fly LN+GELU; 16-row blocks,
// grid (4,128)=512 = 2 blocks/CU.
// NOTE (journal): coop mega-kernel grid.sync ~100us @512WG — abandoned (r5).
// ffn2f with direct-global B + 128 blocks: +10us/dispatch — abandoned (r7).
// N=1024, D=256, H=4, DH=64, L=9. Batched over both images (M=2048).
#define NTOK 1024
#define DM   256
#define NH   4
#define DH   64
#define NL   9

typedef __attribute__((ext_vector_type(8))) __bf16 bf16x8;
typedef __attribute__((ext_vector_type(4))) __bf16 bf16x4;
typedef __attribute__((ext_vector_type(4))) float  f32x4;

__device__ __forceinline__ float logsigf(float x) {
    return fminf(x, 0.0f) - log1pf(expf(-fabsf(x)));
}

__device__ __forceinline__ __bf16 f2bf(float f) {
    unsigned u = __float_as_uint(f);
    u = (u + 0x7FFFu + ((u >> 16) & 1u)) >> 16;          // round-nearest-even
    unsigned short s = (unsigned short)u;
    return __builtin_bit_cast(__bf16, s);
}

// ---------------------------------------------------------------------------
// All weight transposes in ONE dispatch. fp32 [K][N] (batched) -> bf16 [N][K].
// For the qkv group (z<9) output rows are PERMUTED: n' = t*256 + h*64 + d
// (orig n = h*192 + d*3 + t) so the GEMM tile maps 1:1 to (type, head).
// Grid (24, 16, 82).
// ---------------------------------------------------------------------------
__global__ __launch_bounds__(256) void wtrans_all_k(
    const float* __restrict__ sWqkv, const float* __restrict__ sWo,
    const float* __restrict__ sfW1,  const float* __restrict__ sfW2,
    const float* __restrict__ cWqk,  const float* __restrict__ cWv,
    const float* __restrict__ cWo,   const float* __restrict__ cfW1,
    const float* __restrict__ cfW2,  const float* __restrict__ mWp,
    __bf16* __restrict__ wb)
{
    const int z = blockIdx.z;
    const float* src; __bf16* dst; int K, N, b;
    if      (z <  9) { src = sWqkv; dst = wb;            K = 256; N = 768; b = z;      }
    else if (z < 18) { src = sWo;   dst = wb + 1769472;  K = 256; N = 256; b = z - 9;  }
    else if (z < 27) { src = sfW1;  dst = wb + 2359296;  K = 512; N = 512; b = z - 18; }
    else if (z < 36) { src = sfW2;  dst = wb + 4718592;  K = 512; N = 256; b = z - 27; }
    else if (z < 45) { src = cWqk;  dst = wb + 5898240;  K = 256; N = 256; b = z - 36; }
    else if (z < 54) { src = cWv;   dst = wb + 6488064;  K = 256; N = 256; b = z - 45; }
    else if (z < 63) { src = cWo;   dst = wb + 7077888;  K = 256; N = 256; b = z - 54; }
    else if (z < 72) { src = cfW1;  dst = wb + 7667712;  K = 512; N = 512; b = z - 63; }
    else if (z < 81) { src = cfW2;  dst = wb + 10027008; K = 512; N = 256; b = z - 72; }
    else             { src = mWp;   dst = wb + 11206656; K = 256; N = 256; b = 0;      }
    const int n0 = blockIdx.x * 32, k0 = blockIdx.y * 32;
    if (n0 >= N || k0 >= K) return;
    src += (size_t)b * K * N;
    dst += (size_t)b * K * N;

    __shared__ __bf16 t[32][36];
    const int tx = threadIdx.x & 31, ty = threadIdx.x >> 5;
    #pragma unroll
    for (int i = 0; i < 4; ++i) {
        int k = ty + i * 8;
        t[tx][k] = f2bf(src[(size_t)(k0 + k) * N + n0 + tx]);
    }
    __syncthreads();
    const int nr = threadIdx.x >> 3, kc = (threadIdx.x & 7) * 4;
    bf16x4 v = *(const bf16x4*)&t[nr][kc];
    int outr = n0 + nr;
    if (z < 9) {
        int h = outr / 192, r = outr % 192;
        outr = (r % 3) * 256 + h * 64 + (r / 3);
    }
    *(bf16x4*)&dst[(size_t)outr * K + k0 + kc] = v;
}

// ---------------------------------------------------------------------------
// Weight fusion: tW1f[z][o][0:256] = tW1[z][o][0:256] (copy, bx<4);
// tW1f[z][o][256+k] = sum_m tW1[z][o][256+m] * tWo[z][m][k]  (bx>=4, MFMA).
// ---------------------------------------------------------------------------
__global__ __launch_bounds__(256) void wfuse_k(
    const __bf16* __restrict__ tW1s, const __bf16* __restrict__ tWos,
    const __bf16* __restrict__ tW1c, const __bf16* __restrict__ tWoc,
    __bf16* __restrict__ tW1f)
{
    const int z = blockIdx.z, bx = blockIdx.x, tid = threadIdx.x;
    const __bf16* A  = (z < 9) ? tW1s + (size_t)z * 262144 : tW1c + (size_t)(z - 9) * 262144;
    const __bf16* B  = (z < 9) ? tWos + (size_t)z * 65536  : tWoc + (size_t)(z - 9) * 65536;
    __bf16* dst      = tW1f + (size_t)z * 262144;
    const int row0 = blockIdx.y * 32;

    if (bx < 4) {
        const int row = tid >> 3, kc = (tid & 7) * 8;
        bf16x8 v = *(const bf16x8*)&A[(size_t)(row0 + row) * 512 + bx * 64 + kc];
        *(bf16x8*)&dst[(size_t)(row0 + row) * 512 + bx * 64 + kc] = v;
        return;
    }

    __shared__ __bf16 As[8][32][40];
    __shared__ __bf16 Bs[8][64][40];
    const int w = tid >> 6, l = tid & 63;
    const int col0 = (bx - 4) * 64;
    const int wr = (w >> 1) * 16, wc = (w & 1) * 32;
    f32x4 acc0 = {0.f, 0.f, 0.f, 0.f};
    f32x4 acc1 = {0.f, 0.f, 0.f, 0.f};

    const int ar = tid >> 3, ac = (tid & 7) * 4;
    const int tnr = tid >> 3, tkc = (tid & 7) * 8;

    #pragma unroll
    for (int c = 0; c < 8; ++c) {
        bf16x4 av = *(const bf16x4*)&A[(size_t)(row0 + ar) * 512 + 256 + c * 32 + ac];
        *(bf16x4*)&As[c][ar][ac] = av;
        bf16x8 bv = *(const bf16x8*)&B[(size_t)(c * 32 + tnr) * 256 + col0 + tkc];
        #pragma unroll
        for (int e = 0; e < 8; ++e) Bs[c][tkc + e][tnr] = bv[e];
    }
    __syncthreads();
    #pragma unroll
    for (int c = 0; c < 8; ++c) {
        bf16x8 af  = *(const bf16x8*)&As[c][wr + (l & 15)][(l >> 4) * 8];
        bf16x8 bf0 = *(const bf16x8*)&Bs[c][wc + (l & 15)][(l >> 4) * 8];
        bf16x8 bf1 = *(const bf16x8*)&Bs[c][wc + 16 + (l & 15)][(l >> 4) * 8];
        acc0 = __builtin_amdgcn_mfma_f32_16x16x32_bf16(af, bf0, acc0, 0, 0, 0);
        acc1 = __builtin_amdgcn_mfma_f32_16x16x32_bf16(af, bf1, acc1, 0, 0, 0);
    }
    #pragma unroll
    for (int t2 = 0; t2 < 2; ++t2) {
        f32x4 a = t2 ? acc1 : acc0;
        int cc = col0 + wc + t2 * 16 + (l & 15);
        #pragma unroll
        for (int rg = 0; rg < 4; ++rg) {
            int rr = row0 + wr + (l >> 4) * 4 + rg;
            dst[(size_t)rr * 512 + 256 + cc] = f2bf(a[rg]);
        }
    }
}

// bfused[z][o] = b1[z][o] + sum_m bo[z][m] * W1[z][256+m][o]   (fp32)
__global__ __launch_bounds__(256) void bfuse_k(
    const float* __restrict__ sbo, const float* __restrict__ sfW1,
    const float* __restrict__ sfb1, const float* __restrict__ cbo,
    const float* __restrict__ cfW1, const float* __restrict__ cfb1,
    float* __restrict__ bf)
{
    const int z = blockIdx.y;
    const float* bo = (z < 9) ? sbo + z * 256 : cbo + (z - 9) * 256;
    const float* W1 = (z < 9) ? sfW1 + (size_t)z * 262144 : cfW1 + (size_t)(z - 9) * 262144;
    const float* b1 = (z < 9) ? sfb1 + z * 512 : cfb1 + (z - 9) * 512;
    const int o = blockIdx.x * 256 + threadIdx.x;
    float acc = 0.f;
    for (int m = 0; m < 256; ++m)
        acc += bo[m] * W1[(size_t)(256 + m) * 512 + o];
    bf[(size_t)z * 512 + o] = b1[o] + acc;
}

// ---------------------------------------------------------------------------
// qkv GEMM with fused RoPE + head-major bf16 store. A = bf16 xb [2048][256].
// K=256, Nn=768 (permuted: col' = t*256 + h*64 + d). Grid (12, 64).
// RoPE pair d^1 lives in the adjacent column = lane^1 -> __shfl_xor.
// ---------------------------------------------------------------------------
__global__ __launch_bounds__(256) void gemm_qkv_k(
    const __bf16* __restrict__ Ab, const __bf16* __restrict__ Bt,
    const float* __restrict__ bias,   // original order [768]
    const float* __restrict__ encc, const float* __restrict__ encs,
    __bf16* __restrict__ qh, __bf16* __restrict__ kh, __bf16* __restrict__ vh)
{
    __shared__ __bf16 As[8][32][40];
    __shared__ __bf16 Bs[8][64][40];
    const int tid = threadIdx.x;
    const int w = tid >> 6, l = tid & 63;
    const int row0 = blockIdx.y * 32, col0 = blockIdx.x * 64;
    const int wr = (w >> 1) * 16, wc = (w & 1) * 32;
    const int quad = l >> 4, l16 = l & 15;
    f32x4 acc0 = {0.f, 0.f, 0.f, 0.f};
    f32x4 acc1 = {0.f, 0.f, 0.f, 0.f};

    const int ar = tid >> 3, ac = (tid & 7) * 4;
    const int bnr = tid >> 2, bkc = (tid & 3) * 8;

    #pragma unroll
    for (int c = 0; c < 8; ++c) {
        const int k0 = c * 32;
        bf16x4 av = *(const bf16x4*)&Ab[(size_t)(row0 + ar) * 256 + k0 + ac];
        *(bf16x4*)&As[c][ar][ac] = av;
        bf16x8 bv = *(const bf16x8*)&Bt[(size_t)(col0 + bnr) * 256 + k0 + bkc];
        *(bf16x8*)&Bs[c][bnr][bkc] = bv;
    }
    __syncthreads();
    #pragma unroll
    for (int c = 0; c < 8; ++c) {
        bf16x8 af  = *(const bf16x8*)&As[c][wr + l16][quad * 8];
        bf16x8 bf0 = *(const bf16x8*)&Bs[c][wc + l16][quad * 8];
        bf16x8 bf1 = *(const bf16x8*)&Bs[c][wc + 16 + l16][quad * 8];
        acc0 = __builtin_amdgcn_mfma_f32_16x16x32_bf16(af, bf0, acc0, 0, 0, 0);
        acc1 = __builtin_amdgcn_mfma_f32_16x16x32_bf16(af, bf1, acc1, 0, 0, 0);
    }

    // ---- epilogue: bias + RoPE (q,k) + head-major bf16 store ----
    const int typ = col0 >> 8;            // 0=q 1=k 2=v
    const int hh  = (col0 & 255) >> 6;
    __bf16* dst = (typ == 0) ? qh : (typ == 1) ? kh : vh;
    #pragma unroll
    for (int t2 = 0; t2 < 2; ++t2) {
        f32x4 a = t2 ? acc1 : acc0;
        const int d = wc + t2 * 16 + l16;
        const float bvv = bias[hh * 192 + d * 3 + typ];
        float full[4], pair[4];
        #pragma unroll
        for (int rg = 0; rg < 4; ++rg) full[rg] = a[rg] + bvv;
        #pragma unroll
        for (int rg = 0; rg < 4; ++rg) pair[rg] = __shfl_xor(full[rg], 1);
        const float sgn = (d & 1) ? 1.0f : -1.0f;
        #pragma unroll
        for (int rg = 0; rg < 4; ++rg) {
            int rr = row0 + wr + quad * 4 + rg;
            float outv;
            if (typ == 2) {
                outv = full[rg];
            } else {
                float c = encc[(size_t)rr * 64 + d];
                float s = encs[(size_t)rr * 64 + d];
                outv = full[rg] * c + sgn * pair[rg] * s;
            }
            int im = rr >> 10, n = rr & 1023;
            dst[(((size_t)(im * 4 + hh)) * 1024 + n) * 64 + d] = f2bf(outv);
        }
    }
}

// ---------------------------------------------------------------------------
// Deep-staged bf16-MFMA GEMM: C = (A @ B + bias)*scale. bf16 A (ld 256,
// cols<256), OPTIONAL bf16 A1b (cols>=256, ld 256). bf16 B [Nn][K]. fp32 C.
// ---------------------------------------------------------------------------
__global__ __launch_bounds__(256) void gemm_bf_k(
    const __bf16* __restrict__ Ab, const __bf16* __restrict__ A1b,
    const __bf16* __restrict__ Bt, const float* __restrict__ bias,
    float* __restrict__ C, int K, int Nn, int ldc, float scale)
{
    __shared__ __bf16 As[8][32][40];
    __shared__ __bf16 Bs[8][64][40];
    const int tid = threadIdx.x;
    const int w = tid >> 6, l = tid & 63;
    const int row0 = blockIdx.y * 32, col0 = blockIdx.x * 64;
    const int wr = (w >> 1) * 16, wc = (w & 1) * 32;
    f32x4 acc0 = {0.f, 0.f, 0.f, 0.f};
    f32x4 acc1 = {0.f, 0.f, 0.f, 0.f};

    const int ar = tid >> 3, ac = (tid & 7) * 4;
    const int bnr = tid >> 2, bkc = (tid & 3) * 8;

    for (int p0 = 0; p0 < K; p0 += 256) {
        #pragma unroll
        for (int c = 0; c < 8; ++c) {
            const int k0 = p0 + c * 32;
            const int kk = k0 + ac;
            const __bf16* src = (A1b && kk >= 256)
                ? &A1b[(size_t)(row0 + ar) * 256 + (kk - 256)]
                : &Ab[(size_t)(row0 + ar) * 256 + kk];
            bf16x4 av = *(const bf16x4*)src;
            *(bf16x4*)&As[c][ar][ac] = av;
            bf16x8 bv = *(const bf16x8*)&Bt[(size_t)(col0 + bnr) * K + k0 + bkc];
            *(bf16x8*)&Bs[c][bnr][bkc] = bv;
        }
        __syncthreads();
        #pragma unroll
        for (int c = 0; c < 8; ++c) {
            bf16x8 af  = *(const bf16x8*)&As[c][wr + (l & 15)][(l >> 4) * 8];
            bf16x8 bf0 = *(const bf16x8*)&Bs[c][wc + (l & 15)][(l >> 4) * 8];
            bf16x8 bf1 = *(const bf16x8*)&Bs[c][wc + 16 + (l & 15)][(l >> 4) * 8];
            acc0 = __builtin_amdgcn_mfma_f32_16x16x32_bf16(af, bf0, acc0, 0, 0, 0);
            acc1 = __builtin_amdgcn_mfma_f32_16x16x32_bf16(af, bf1, acc1, 0, 0, 0);
        }
        __syncthreads();
    }

    #pragma unroll
    for (int t2 = 0; t2 < 2; ++t2) {
        f32x4 a = t2 ? acc1 : acc0;
        int cc = col0 + wc + t2 * 16 + (l & 15);
        float bvv = bias ? bias[cc] : 0.0f;
        #pragma unroll
        for (int rg = 0; rg < 4; ++rg) {
            int rr = row0 + wr + (l >> 4) * 4 + rg;
            C[(size_t)rr * ldc + cc] = (a[rg] + bvv) * scale;
        }
    }
}

// ---------------------------------------------------------------------------
// Head projection GEMM with bf16 output: Cb = f2bf((A @ B + bias)*scale).
// bf16 A [M][256], bf16 B [Nn][256], K=256 single phase. Grid (4, 64).
// ---------------------------------------------------------------------------
__global__ __launch_bounds__(256) void gemm_bfb_k(
    const __bf16* __restrict__ Ab, const __bf16* __restrict__ Bt,
    const float* __restrict__ bias, __bf16* __restrict__ Cb, float scale)
{
    __shared__ __bf16 As[8][32][40];
    __shared__ __bf16 Bs[8][64][40];
    const int tid = threadIdx.x;
    const int w = tid >> 6, l = tid & 63;
    const int row0 = blockIdx.y * 32, col0 = blockIdx.x * 64;
    const int wr = (w >> 1) * 16, wc = (w & 1) * 32;
    f32x4 acc0 = {0.f, 0.f, 0.f, 0.f};
    f32x4 acc1 = {0.f, 0.f, 0.f, 0.f};

    const int ar = tid >> 3, ac = (tid & 7) * 4;
    const int bnr = tid >> 2, bkc = (tid & 3) * 8;

    #pragma unroll
    for (int c = 0; c < 8; ++c) {
        const int k0 = c * 32;
        bf16x4 av = *(const bf16x4*)&Ab[(size_t)(row0 + ar) * 256 + k0 + ac];
        *(bf16x4*)&As[c][ar][ac] = av;
        bf16x8 bv = *(const bf16x8*)&Bt[(size_t)(col0 + bnr) * 256 + k0 + bkc];
        *(bf16x8*)&Bs[c][bnr][bkc] = bv;
    }
    __syncthreads();
    #pragma unroll
    for (int c = 0; c < 8; ++c) {
        bf16x8 af  = *(const bf16x8*)&As[c][wr + (l & 15)][(l >> 4) * 8];
        bf16x8 bf0 = *(const bf16x8*)&Bs[c][wc + (l & 15)][(l >> 4) * 8];
        bf16x8 bf1 = *(const bf16x8*)&Bs[c][wc + 16 + (l & 15)][(l >> 4) * 8];
        acc0 = __builtin_amdgcn_mfma_f32_16x16x32_bf16(af, bf0, acc0, 0, 0, 0);
        acc1 = __builtin_amdgcn_mfma_f32_16x16x32_bf16(af, bf1, acc1, 0, 0, 0);
    }

    #pragma unroll
    for (int t2 = 0; t2 < 2; ++t2) {
        f32x4 a = t2 ? acc1 : acc0;
        int cc = col0 + wc + t2 * 16 + (l & 15);
        float bvv = bias[cc];
        #pragma unroll
        for (int rg = 0; rg < 4; ++rg) {
            int rr = row0 + wr + (l >> 4) * 4 + rg;
            Cb[(size_t)rr * 256 + cc] = f2bf((a[rg] + bvv) * scale);
        }
    }
}

// ---------------------------------------------------------------------------
// Fused LN(512)+GELU+FFN2 v3: proven gemm_bfa structure (LDS-staged B,
// 64-col tiles, per-phase sync); A operand from on-the-fly LN+GELU.
// Block = 16 rows x 64 cols; grid (4,128) = 512 blocks = 2 blocks/CU
// (LDS 61440 B). Thread (r=tid>>4, sub=tid&15) owns pre[row0+r][sub*32..+32):
// LN stats via 16-lane shfl (aligned groups), GELU once, stored to
// As[p=sub>>3][c=sub&7][r][j] so k = p*256+c*32+j matches the MFMA read.
// Epilogue: +bias +residual -> x, xb.
// ---------------------------------------------------------------------------
__global__ __launch_bounds__(256) void ffn3_k(
    const float* __restrict__ pre, const float* __restrict__ g,
    const float* __restrict__ beta, const __bf16* __restrict__ Bt,
    const float* __restrict__ bias, float* __restrict__ x,
    __bf16* __restrict__ xb)
{
    __shared__ __bf16 As[2][8][16][40];   // both K-phases, 20480 B
    __shared__ __bf16 Bs[8][64][40];      // per-phase B tile, 40960 B
    const int tid = threadIdx.x;
    const int row0 = blockIdx.y * 16, col0 = blockIdx.x * 64;

    // ---- LN stats: 16 threads per row, shfl reduce over aligned 16-group ----
    const int r = tid >> 4, sub = tid & 15;
    float v[32];
    const float* pr = pre + (size_t)(row0 + r) * 512 + sub * 32;
    float s = 0.f;
    #pragma unroll
    for (int j4 = 0; j4 < 8; ++j4) {
        float4 t = *(const float4*)&pr[j4 * 4];
        v[j4 * 4 + 0] = t.x; v[j4 * 4 + 1] = t.y;
        v[j4 * 4 + 2] = t.z; v[j4 * 4 + 3] = t.w;
        s += t.x + t.y + t.z + t.w;
    }
    #pragma unroll
    for (int ofs = 1; ofs < 16; ofs <<= 1) s += __shfl_xor(s, ofs);
    const float mu = s * (1.0f / 512.0f);
    float ss = 0.f;
    #pragma unroll
    for (int j = 0; j < 32; ++j) { float d = v[j] - mu; ss += d * d; }
    #pragma unroll
    for (int ofs = 1; ofs < 16; ofs <<= 1) ss += __shfl_xor(ss, ofs);
    const float rstd = rsqrtf(ss * (1.0f / 512.0f) + 1e-5f);

    // ---- GELU once; store h into As in MFMA-A layout ----
    const int p = sub >> 3, c = sub & 7;
    const float IS2 = 0.70710678118654752f;
    #pragma unroll
    for (int j8 = 0; j8 < 4; ++j8) {
        bf16x8 hb;
        #pragma unroll
        for (int e4 = 0; e4 < 2; ++e4) {
            float4 gg = *(const float4*)&g[sub * 32 + j8 * 8 + e4 * 4];
            float4 bb = *(const float4*)&beta[sub * 32 + j8 * 8 + e4 * 4];
            int j = j8 * 8 + e4 * 4;
            float y;
            y = (v[j+0] - mu) * rstd * gg.x + bb.x;
            hb[e4*4+0] = f2bf(0.5f * y * (1.0f + erff(y * IS2)));
            y = (v[j+1] - mu) * rstd * gg.y + bb.y;
            hb[e4*4+1] = f2bf(0.5f * y * (1.0f + erff(y * IS2)));
            y = (v[j+2] - mu) * rstd * gg.z + bb.z;
            hb[e4*4+2] = f2bf(0.5f * y * (1.0f + erff(y * IS2)));
            y = (v[j+3] - mu) * rstd * gg.w + bb.w;
            hb[e4*4+3] = f2bf(0.5f * y * (1.0f + erff(y * IS2)));
        }
        *(bf16x8*)&As[p][c][r][j8 * 8] = hb;
    }

    // ---- GEMM 16 x 64, K=512 in 2 phases; B staged in LDS (proven path) ----
    const int w = tid >> 6, l = tid & 63;
    const int quad = l >> 4, l16 = l & 15;
    f32x4 acc = {0.f, 0.f, 0.f, 0.f};
    const int bnr = tid >> 2, bkc = (tid & 3) * 8;

    for (int p2 = 0; p2 < 2; ++p2) {
        #pragma unroll
        for (int c2 = 0; c2 < 8; ++c2) {
            const int k0 = p2 * 256 + c2 * 32;
            bf16x8 bv = *(const bf16x8*)&Bt[(size_t)(col0 + bnr) * 512 + k0 + bkc];
            *(bf16x8*)&Bs[c2][bnr][bkc] = bv;
        }
        __syncthreads();
        #pragma unroll
        for (int c2 = 0; c2 < 8; ++c2) {
            bf16x8 af = *(const bf16x8*)&As[p2][c2][l16][quad * 8];
            bf16x8 bf = *(const bf16x8*)&Bs[c2][w * 16 + l16][quad * 8];
            acc = __builtin_amdgcn_mfma_f32_16x16x32_bf16(af, bf, acc, 0, 0, 0);
        }
        __syncthreads();
    }

    // ---- epilogue: bias + residual -> x, xb ----
    {
        int cc = col0 + w * 16 + l16;
        float bvv = bias[cc];
        #pragma unroll
        for (int rg = 0; rg < 4; ++rg) {
            int rr = row0 + quad * 4 + rg;
            float outv = acc[rg] + bvv + x[(size_t)rr * 256 + cc];
            x[(size_t)rr * 256 + cc]  = outv;
            xb[(size_t)rr * 256 + cc] = f2bf(outv);
        }
    }
}

// ---------------------------------------------------------------------------
// Cross qk+v fused GEMM (deep-staged, K=256): grid (8, 64). bx<4 -> Wq, else Wv.
// A = bf16 xb.
// ---------------------------------------------------------------------------
__global__ __launch_bounds__(256) void gemm_hm2_k(
    const __bf16* __restrict__ Ab, const __bf16* __restrict__ Btq,
    const float* __restrict__ bq, const __bf16* __restrict__ Btv,
    const float* __restrict__ bv, __bf16* __restrict__ outq,
    __bf16* __restrict__ outv, float scaleq)
{
    const int bx = blockIdx.x;
    const __bf16* Bt  = (bx < 4) ? Btq : Btv;
    const float* bias = (bx < 4) ? bq : bv;
    __bf16* C         = (bx < 4) ? outq : outv;
    const float scale = (bx < 4) ? scaleq : 1.0f;

    __shared__ __bf16 As[8][32][40];
    __shared__ __bf16 Bs[8][64][40];
    const int tid = threadIdx.x;
    const int w = tid >> 6, l = tid & 63;
    const int row0 = blockIdx.y * 32, col0 = (bx & 3) * 64;
    const int wr = (w >> 1) * 16, wc = (w & 1) * 32;
    f32x4 acc0 = {0.f, 0.f, 0.f, 0.f};
    f32x4 acc1 = {0.f, 0.f, 0.f, 0.f};

    const int ar = tid >> 3, ac = (tid & 7) * 4;
    const int bnr = tid >> 2, bkc = (tid & 3) * 8;

    #pragma unroll
    for (int c = 0; c < 8; ++c) {
        const int k0 = c * 32;
        bf16x4 av = *(const bf16x4*)&Ab[(size_t)(row0 + ar) * 256 + k0 + ac];
        *(bf16x4*)&As[c][ar][ac] = av;
        bf16x8 bv8 = *(const bf16x8*)&Bt[(size_t)(col0 + bnr) * 256 + k0 + bkc];
        *(bf16x8*)&Bs[c][bnr][bkc] = bv8;
    }
    __syncthreads();
    #pragma unroll
    for (int c = 0; c < 8; ++c) {
        bf16x8 af  = *(const bf16x8*)&As[c][wr + (l & 15)][(l >> 4) * 8];
        bf16x8 bf0 = *(const bf16x8*)&Bs[c][wc + (l & 15)][(l >> 4) * 8];
        bf16x8 bf1 = *(const bf16x8*)&Bs[c][wc + 16 + (l & 15)][(l >> 4) * 8];
        acc0 = __builtin_amdgcn_mfma_f32_16x16x32_bf16(af, bf0, acc0, 0, 0, 0);
        acc1 = __builtin_amdgcn_mfma_f32_16x16x32_bf16(af, bf1, acc1, 0, 0, 0);
    }

    #pragma unroll
    for (int t2 = 0; t2 < 2; ++t2) {
        f32x4 a = t2 ? acc1 : acc0;
        int cc = col0 + wc + t2 * 16 + (l & 15);
        float bvv = bias ? bias[cc] : 0.0f;
        int h = cc >> 6, d = cc & 63;
        #pragma unroll
        for (int rg = 0; rg < 4; ++rg) {
            int rr = row0 + wr + (l >> 4) * 4 + rg;
            int im = rr >> 10, n = rr & 1023;
            C[(((size_t)(im * 4 + h)) * 1024 + n) * 64 + d] = f2bf((a[rg] + bvv) * scale);
        }
    }
}

// ---------------------------------------------------------------------------
// sim = A @ B^T, bf16 A,B (mdb halves), K=256 single phase, fp32 C.
// Grid (16, 32).
// ---------------------------------------------------------------------------
__global__ __launch_bounds__(256) void gemm_bt_k(
    const __bf16* __restrict__ Ab, const __bf16* __restrict__ Bb,
    float* __restrict__ C, int Nn)
{
    __shared__ __bf16 As[8][32][40];
    __shared__ __bf16 Bs[8][64][40];
    const int tid = threadIdx.x;
    const int w = tid >> 6, l = tid & 63;
    const int row0 = blockIdx.y * 32, col0 = blockIdx.x * 64;
    const int wr = (w >> 1) * 16, wc = (w & 1) * 32;
    f32x4 acc0 = {0.f, 0.f, 0.f, 0.f};
    f32x4 acc1 = {0.f, 0.f, 0.f, 0.f};

    const int ar = tid >> 3, ac = (tid & 7) * 4;
    const int bnr = tid >> 2, bkc = (tid & 3) * 8;

    #pragma unroll
    for (int c = 0; c < 8; ++c) {
        const int k0 = c * 32;
        bf16x4 av = *(const bf16x4*)&Ab[(size_t)(row0 + ar) * 256 + k0 + ac];
        *(bf16x4*)&As[c][ar][ac] = av;
        bf16x8 bv = *(const bf16x8*)&Bb[(size_t)(col0 + bnr) * 256 + k0 + bkc];
        *(bf16x8*)&Bs[c][bnr][bkc] = bv;
    }
    __syncthreads();
    #pragma unroll
    for (int c = 0; c < 8; ++c) {
        bf16x8 af  = *(const bf16x8*)&As[c][wr + (l & 15)][(l >> 4) * 8];
        bf16x8 bf0 = *(const bf16x8*)&Bs[c][wc + (l & 15)][(l >> 4) * 8];
        bf16x8 bf1 = *(const bf16x8*)&Bs[c][wc + 16 + (l & 15)][(l >> 4) * 8];
        acc0 = __builtin_amdgcn_mfma_f32_16x16x32_bf16(af, bf0, acc0, 0, 0, 0);
        acc1 = __builtin_amdgcn_mfma_f32_16x16x32_bf16(af, bf1, acc1, 0, 0, 0);
    }

    #pragma unroll
    for (int t2 = 0; t2 < 2; ++t2) {
        f32x4 a = t2 ? acc1 : acc0;
        int cc = col0 + wc + t2 * 16 + (l & 15);
        #pragma unroll
        for (int rg = 0; rg < 4; ++rg) {
            int rr = row0 + wr + (l >> 4) * 4 + rg;
            C[(size_t)rr * Nn + cc] = a[rg];
        }
    }
}

// ---------------------------------------------------------------------------
// Fused init: desc copies (fp32 + bf16 mirror) + posenc. Grid 2304 x 256.
// ---------------------------------------------------------------------------
__global__ __launch_bounds__(256) void init_k(
    const float* __restrict__ desc0, const float* __restrict__ desc1,
    const float* __restrict__ kpts0, const float* __restrict__ kpts1,
    const float* __restrict__ Wr, float* __restrict__ x,
    __bf16* __restrict__ xb,
    float* __restrict__ encc, float* __restrict__ encs)
{
    int idx = blockIdx.x * 256 + threadIdx.x;
    if (idx < 524288) {
        float v = (idx < 262144) ? desc0[idx] : desc1[idx - 262144];
        x[idx]  = v;
        xb[idx] = f2bf(v);
    } else {
        int p = idx - 524288;
        int im = p >> 15, q = p & 32767;
        int i = q >> 5, f = q & 31;
        const float* kp = im ? kpts1 : kpts0;
        float* ec = encc + im * 65536;
        float* es = encs + im * 65536;
        float pr = kp[i * 2] * Wr[f] + kp[i * 2 + 1] * Wr[32 + f];
        float c = cosf(pr), s = sinf(pr);
        ec[i * 64 + 2 * f] = c; ec[i * 64 + 2 * f + 1] = c;
        es[i * 64 + 2 * f] = s; es[i * 64 + 2 * f + 1] = s;
    }
}

// ---------------------------------------------------------------------------
// Attention v6: flash-style bf16 MFMA with K/V register prefetch pipelining.
// Output msg written bf16 [2048][256].
// ---------------------------------------------------------------------------
__global__ __launch_bounds__(256) void attn_k(
    const __bf16* __restrict__ Qg, const __bf16* __restrict__ Kg,
    const __bf16* __restrict__ Vg, __bf16* __restrict__ out,
    float scale, int cross)
{
    const int qt = blockIdx.x, hv = blockIdx.y;
    const int kvh = cross ? (hv ^ 4) : hv;
    const int tid = threadIdx.x;
    const int w = tid >> 6, lane = tid & 63;
    const int quad = lane >> 4, l16 = lane & 15;
    const int n0 = qt * 16;

    __shared__ __align__(16) char smem[44032];
    char* base = smem + w * 11008;
    __bf16* kb  = (__bf16*)(base);          // 32 x 72
    __bf16* vtb = (__bf16*)(base + 4608);   // 64 x 40
    __bf16* ptb = (__bf16*)(base + 9728);   // 16 x 40

    bf16x8 qf[2];
    {
        const bf16x8* Qp = (const bf16x8*)(Qg + (((size_t)hv * 1024) + n0 + l16) * 64);
        qf[0] = Qp[quad];
        qf[1] = Qp[4 + quad];
    }

    const __bf16* Kbase = Kg + (size_t)kvh * 1024 * 64;
    const __bf16* Vbase = Vg + (size_t)kvh * 1024 * 64;

    float m[4] = {-1e30f, -1e30f, -1e30f, -1e30f};
    float lsum[4] = {0.f, 0.f, 0.f, 0.f};
    f32x4 o[4] = {{0,0,0,0},{0,0,0,0},{0,0,0,0},{0,0,0,0}};

    const int kj = lane >> 1, kd = (lane & 1) * 32;
    const int vjp = lane & 15, vd0 = (lane >> 4) * 16;

    bf16x8 kr[4];
    uint4  vr[4];
    {
        const int j0 = w * 256;
        const bf16x8* kp = (const bf16x8*)(Kbase + (size_t)(j0 + kj) * 64 + kd);
        kr[0] = kp[0]; kr[1] = kp[1]; kr[2] = kp[2]; kr[3] = kp[3];
        const uint4* va = (const uint4*)(Vbase + (size_t)(j0 + 2 * vjp) * 64 + vd0);
        const uint4* vb = (const uint4*)(Vbase + (size_t)(j0 + 2 * vjp + 1) * 64 + vd0);
        vr[0] = va[0]; vr[1] = va[1]; vr[2] = vb[0]; vr[3] = vb[1];
    }

    for (int t = 0; t < 8; ++t) {
        {
            __bf16* krow = kb + kj * 72 + kd;
            *(bf16x8*)(krow)      = kr[0];
            *(bf16x8*)(krow + 8)  = kr[1];
            *(bf16x8*)(krow + 16) = kr[2];
            *(bf16x8*)(krow + 24) = kr[3];
            #pragma unroll
            for (int g = 0; g < 2; ++g) {
                uint4 ua = vr[g], ub = vr[2 + g];
                unsigned au[4] = {ua.x, ua.y, ua.z, ua.w};
                unsigned bu[4] = {ub.x, ub.y, ub.z, ub.w};
                #pragma unroll
                for (int e = 0; e < 4; ++e) {
                    int i = g * 8 + e * 2;
                    unsigned pk0 = ((bu[e] & 0xFFFFu) << 16) | (au[e] & 0xFFFFu);
                    unsigned pk1 = (bu[e] & 0xFFFF0000u) | (au[e] >> 16);
                    *(unsigned*)((char*)vtb + ((vd0 + i) * 40 + 2 * vjp) * 2)     = pk0;
                    *(unsigned*)((char*)vtb + ((vd0 + i + 1) * 40 + 2 * vjp) * 2) = pk1;
                }
            }
        }
        if (t < 7) {
            const int j1 = w * 256 + (t + 1) * 32;
            const bf16x8* kp = (const bf16x8*)(Kbase + (size_t)(j1 + kj) * 64 + kd);
            kr[0] = kp[0]; kr[1] = kp[1]; kr[2] = kp[2]; kr[3] = kp[3];
            const uint4* va = (const uint4*)(Vbase + (size_t)(j1 + 2 * vjp) * 64 + vd0);
            const uint4* vb = (const uint4*)(Vbase + (size_t)(j1 + 2 * vjp + 1) * 64 + vd0);
            vr[0] = va[0]; vr[1] = va[1]; vr[2] = vb[0]; vr[3] = vb[1];
        }

        f32x4 s0 = {0,0,0,0}, s1 = {0,0,0,0};
        #pragma unroll
        for (int kt = 0; kt < 2; ++kt) {
            bf16x8 k0 = *(const bf16x8*)(kb + (0 * 16 + l16) * 72 + kt * 32 + quad * 8);
            bf16x8 k1 = *(const bf16x8*)(kb + (1 * 16 + l16) * 72 + kt * 32 + quad * 8);
            s0 = __builtin_amdgcn_mfma_f32_16x16x32_bf16(qf[kt], k0, s0, 0, 0, 0);
            s1 = __builtin_amdgcn_mfma_f32_16x16x32_bf16(qf[kt], k1, s1, 0, 0, 0);
        }

        float rm[4], p0[4], p1[4], rs[4];
        #pragma unroll
        for (int r = 0; r < 4; ++r) {
            s0[r] *= scale; s1[r] *= scale;
            rm[r] = fmaxf(s0[r], s1[r]);
        }
        #pragma unroll
        for (int ofs = 1; ofs < 16; ofs <<= 1)
            #pragma unroll
            for (int r = 0; r < 4; ++r)
                rm[r] = fmaxf(rm[r], __shfl_xor(rm[r], ofs));
        #pragma unroll
        for (int r = 0; r < 4; ++r) {
            float mn = fmaxf(m[r], rm[r]);
            float alpha = __expf(m[r] - mn);
            m[r] = mn;
            p0[r] = __expf(s0[r] - mn);
            p1[r] = __expf(s1[r] - mn);
            rs[r] = p0[r] + p1[r];
            lsum[r] *= alpha;
            #pragma unroll
            for (int dt = 0; dt < 4; ++dt) o[dt][r] *= alpha;
        }
        #pragma unroll
        for (int ofs = 1; ofs < 16; ofs <<= 1)
            #pragma unroll
            for (int r = 0; r < 4; ++r)
                rs[r] += __shfl_xor(rs[r], ofs);
        #pragma unroll
        for (int r = 0; r < 4; ++r) lsum[r] += rs[r];

        #pragma unroll
        for (int r = 0; r < 4; ++r) {
            ptb[(quad * 4 + r) * 40 + l16]      = f2bf(p0[r]);
            ptb[(quad * 4 + r) * 40 + 16 + l16] = f2bf(p1[r]);
        }
        bf16x8 pf = *(const bf16x8*)(ptb + l16 * 40 + quad * 8);
        #pragma unroll
        for (int dt = 0; dt < 4; ++dt) {
            bf16x8 vf = *(const bf16x8*)(vtb + (dt * 16 + l16) * 40 + quad * 8);
            o[dt] = __builtin_amdgcn_mfma_f32_16x16x32_bf16(pf, vf, o[dt], 0, 0, 0);
        }
    }

    __syncthreads();
    float* Om = (float*)smem;          // [64][64] : row = w*16 + q
    float* mm = Om + 4096;             // [64]
    float* lm = mm + 64;               // [64]
    #pragma unroll
    for (int dt = 0; dt < 4; ++dt)
        #pragma unroll
        for (int r = 0; r < 4; ++r)
            Om[(w * 16 + quad * 4 + r) * 64 + dt * 16 + l16] = o[dt][r];
    if (l16 == 0) {
        #pragma unroll
        for (int r = 0; r < 4; ++r) {
            mm[w * 16 + quad * 4 + r] = m[r];
            lm[w * 16 + quad * 4 + r] = lsum[r];
        }
    }
    __syncthreads();

    const int q = tid >> 4, dg = tid & 15;
    float M = -1e30f;
    #pragma unroll
    for (int w2 = 0; w2 < 4; ++w2) M = fmaxf(M, mm[w2 * 16 + q]);
    float L = 0.f;
    float4 acc = {0.f, 0.f, 0.f, 0.f};
    #pragma unroll
    for (int w2 = 0; w2 < 4; ++w2) {
        float e = __expf(mm[w2 * 16 + q] - M);
        L += e * lm[w2 * 16 + q];
        float4 ov = *(const float4*)&Om[(w2 * 16 + q) * 64 + dg * 4];
        acc.x += e * ov.x; acc.y += e * ov.y; acc.z += e * ov.z; acc.w += e * ov.w;
    }
    float inv = 1.0f / L;
    bf16x4 ob;
    ob[0] = f2bf(acc.x * inv); ob[1] = f2bf(acc.y * inv);
    ob[2] = f2bf(acc.z * inv); ob[3] = f2bf(acc.w * inv);
    int row = (hv >> 2) * 1024 + n0 + q;
    *(bf16x4*)&out[(size_t)row * 256 + (hv & 3) * 64 + dg * 4] = ob;
}

// z = x @ Wz + bz : wave-per-row, float4 + shfl reduce. Grid 512.
__global__ __launch_bounds__(256) void z_k(
    const float* __restrict__ x, const float* __restrict__ Wz,
    const float* __restrict__ bz, float* __restrict__ z)
{
    int row = blockIdx.x * 4 + (threadIdx.x >> 6);
    int lane = threadIdx.x & 63;
    float4 v  = *(const float4*)&x[(size_t)row * 256 + lane * 4];
    float4 wv = *(const float4*)&Wz[lane * 4];
    float s = v.x * wv.x + v.y * wv.y + v.z * wv.z + v.w * wv.w;
    #pragma unroll
    for (int ofs = 1; ofs < 64; ofs <<= 1) s += __shfl_xor(s, ofs);
    if (lane == 0) z[row] = s + bz[0];
}

// Row lse (blocks 0..1023) and col lse (blocks 1024..2047) in one dispatch.
__global__ __launch_bounds__(256) void lse_k(
    const float* __restrict__ sim, float* __restrict__ rls,
    float* __restrict__ cls)
{
    const int b = blockIdx.x, t = threadIdx.x;
    const int isCol = b >> 10, rc = b & 1023;
    const size_t base = isCol ? (size_t)rc : (size_t)rc * 1024;
    const size_t stride = isCol ? 1024 : 1;
    __shared__ float red[256];
    float mx = -1e30f;
    for (int j = t; j < NTOK; j += 256) mx = fmaxf(mx, sim[base + stride * j]);
    red[t] = mx; __syncthreads();
    for (int s = 128; s > 0; s >>= 1) {
        if (t < s) red[t] = fmaxf(red[t], red[t + s]);
        __syncthreads();
    }
    mx = red[0]; __syncthreads();
    float sum = 0.0f;
    for (int j = t; j < NTOK; j += 256) sum += expf(sim[base + stride * j] - mx);
    red[t] = sum; __syncthreads();
    for (int s = 128; s > 0; s >>= 1) {
        if (t < s) red[t] += red[t + s];
        __syncthreads();
    }
    if (t == 0) (isCol ? cls : rls)[rc] = mx + logf(red[0]);
}

__global__ __launch_bounds__(256) void assemble_k(
    const float* __restrict__ sim, const float* __restrict__ rls,
    const float* __restrict__ cls, const float* __restrict__ z0,
    const float* __restrict__ z1, float* __restrict__ out)
{
    int idx = blockIdx.x * 256 + threadIdx.x;
    const int W = NTOK + 1;
    if (idx >= W * W) return;
    int i = idx / W, j = idx % W;
    float v;
    if (i < NTOK && j < NTOK) {
        v = 2.0f * sim[(size_t)i * NTOK + j] - rls[i] - cls[j] + logsigf(z0[i]) + logsigf(z1[j]);
    } else if (i < NTOK) {
        v = logsigf(-z0[i]);
    } else if (j < NTOK) {
        v = logsigf(-z1[j]);
    } else {
        v = 0.0f;
    }
    out[idx] = v;
}

// ---------------------------------------------------------------------------
extern "C" void kernel_launch(void* const* d_in, const int* in_sizes, int n_in,
                              void* d_out, int out_size, void* d_ws, size_t ws_size,
                              hipStream_t stream)
{
    const float* desc0 = (const float*)d_in[0];
    const float* desc1 = (const float*)d_in[1];
    const float* kpts0 = (const float*)d_in[2];
    const float* kpts1 = (const float*)d_in[3];
    const float* Wr    = (const float*)d_in[4];
    const float* sWqkv = (const float*)d_in[5];
    const float* sbqkv = (const float*)d_in[6];
    const float* sWo   = (const float*)d_in[7];
    const float* sbo   = (const float*)d_in[8];
    const float* sfW1  = (const float*)d_in[9];
    const float* sfb1  = (const float*)d_in[10];
    const float* sfg   = (const float*)d_in[11];
    const float* sfbt  = (const float*)d_in[12];
    const float* sfW2  = (const float*)d_in[13];
    const float* sfb2  = (const float*)d_in[14];
    const float* cWqk  = (const float*)d_in[15];
    const float* cbqk  = (const float*)d_in[16];
    const float* cWv   = (const float*)d_in[17];
    const float* cbv   = (const float*)d_in[18];
    const float* cWo   = (const float*)d_in[19];
    const float* cbo   = (const float*)d_in[20];
    const float* cfW1  = (const float*)d_in[21];
    const float* cfb1  = (const float*)d_in[22];
    const float* cfg   = (const float*)d_in[23];
    const float* cfbt  = (const float*)d_in[24];
    const float* cfW2  = (const float*)d_in[25];
    const float* cfb2  = (const float*)d_in[26];
    const float* mWp   = (const float*)d_in[27];
    const float* mbp   = (const float*)d_in[28];
    const float* mWz   = (const float*)d_in[29];
    const float* mbz   = (const float*)d_in[30];

    float* ws = (float*)d_ws;
    // Layout (float units):
    float*  x    = ws;                      // 524288  [2048][256] fp32
    float*  encc = ws + 524288;             // 131072  [2048][64]
    float*  encs = ws + 655360;             // 131072
    float*  pre  = ws + 786432;             // 1048576 [2048][512] fp32
    __bf16* qh   = (__bf16*)(ws + 2359296); // 262144 fl
    __bf16* kh   = (__bf16*)(ws + 2621440); // 262144 fl
    __bf16* vh   = (__bf16*)(ws + 2883584); // 262144 fl
    __bf16* msgb = (__bf16*)(ws + 3145728); // 131072 fl = [2048][256] bf16
    float*  zb   = ws + 3276800;            // 2048
    float*  rlsb = ws + 3278848;            // 1024
    float*  clsb = ws + 3279872;            // 1024
    float*  sim  = pre;                     // 1048576 (assignment; pre dead)
    __bf16* mdb  = (__bf16*)(ws + 1835008); // [2048][256] bf16 (assignment)

    // bf16 pre-transposed weights [N][K]
    __bf16* wb    = (__bf16*)(ws + 3280896);
    __bf16* tWqkv = wb;                     // 9*768*256 (rows permuted t*256+h*64+d)
    __bf16* tWo   = tWqkv + 1769472;
    __bf16* tW1   = tWo   + 589824;
    __bf16* tW2   = tW1   + 2359296;
    __bf16* tcQk  = tW2   + 1179648;
    __bf16* tcV   = tcQk  + 589824;
    __bf16* tcWo  = tcV   + 589824;
    __bf16* tcW1  = tcWo  + 589824;
    __bf16* tcW2  = tcW1  + 2359296;
    __bf16* tmWp  = tcW2  + 1179648;        // 65536   (wb total 11272192 bf16)
    __bf16* tW1f  = (__bf16*)(ws + 8916992);   // 4718592 bf16 = 2359296 fl
    float*  bfb   = ws + 11276288;             // 18*512 = 9216 fl
    __bf16* xb    = (__bf16*)(ws + 11285504);  // 524288 bf16 = 262144 fl (total ~46.2 MB)

    // ---- one-time: transposes (+qkv perm), weight fusion, bias fusion ----
    wtrans_all_k<<<dim3(24, 16, 82), 256, 0, stream>>>(
        sWqkv, sWo, sfW1, sfW2, cWqk, cWv, cWo, cfW1, cfW2, mWp, wb);
    wfuse_k<<<dim3(8, 16, 18), 256, 0, stream>>>(tW1, tWo, tcW1, tcWo, tW1f);
    bfuse_k<<<dim3(2, 18), 256, 0, stream>>>(sbo, sfW1, sfb1, cbo, cfW1, cfb1, bfb);

    const float SELF_SCALE  = 0.125f;               // DH^-0.5
    const float CROSS_SCALE = 0.35355339059327373f; // DH^-0.25

    init_k<<<2304, 256, 0, stream>>>(desc0, desc1, kpts0, kpts1, Wr, x, xb, encc, encs);

    for (int l = 0; l < NL; ++l) {
        // ---- self block ----
        gemm_qkv_k<<<dim3(12, 64), 256, 0, stream>>>(
            xb, tWqkv + (size_t)l * 196608, sbqkv + (size_t)l * 768,
            encc, encs, qh, kh, vh);
        attn_k<<<dim3(64, 8), 256, 0, stream>>>(qh, kh, vh, msgb, SELF_SCALE, 0);
        gemm_bf_k<<<dim3(8, 64), 256, 0, stream>>>(
            xb, msgb, tW1f + (size_t)l * 262144, bfb + (size_t)l * 512,
            pre, 512, 512, 512, 1.0f);
        ffn3_k<<<dim3(4, 128), 256, 0, stream>>>(
            pre, sfg + (size_t)l * 512, sfbt + (size_t)l * 512,
            tW2 + (size_t)l * 131072, sfb2 + (size_t)l * 256, x, xb);

        // ---- cross block ----
        gemm_hm2_k<<<dim3(8, 64), 256, 0, stream>>>(
            xb, tcQk + (size_t)l * 65536, cbqk + (size_t)l * 256,
            tcV + (size_t)l * 65536, cbv + (size_t)l * 256,
            qh, vh, CROSS_SCALE);
        attn_k<<<dim3(64, 8), 256, 0, stream>>>(qh, qh, vh, msgb, 1.0f, 1);
        gemm_bf_k<<<dim3(8, 64), 256, 0, stream>>>(
            xb, msgb, tW1f + (size_t)(9 + l) * 262144, bfb + (size_t)(9 + l) * 512,
            pre, 512, 512, 512, 1.0f);
        ffn3_k<<<dim3(4, 128), 256, 0, stream>>>(
            pre, cfg + (size_t)l * 512, cfbt + (size_t)l * 512,
            tcW2 + (size_t)l * 131072, cfb2 + (size_t)l * 256, x, xb);
    }

    // ---- assignment head ----
    const float MD_SCALE = 0.25f; // D^-0.25
    gemm_bfb_k<<<dim3(4, 64), 256, 0, stream>>>(xb, tmWp, mbp, mdb, MD_SCALE);
    z_k<<<512, 256, 0, stream>>>(x, mWz, mbz, zb);
    gemm_bt_k<<<dim3(16, 32), 256, 0, stream>>>(mdb, mdb + 1024 * 256, sim, 1024);
    lse_k<<<2048, 256, 0, stream>>>(sim, rlsb, clsb);
    const int W = NTOK + 1;
    assemble_k<<<(W * W + 255) / 256, 256, 0, stream>>>(sim, rlsb, clsb, zb, zb + 1024, (float*)d_out);
}

// Round 9
// 927.749 us; speedup vs baseline: 1.1965x; 1.0439x over previous
//
#include <hip/hip_runtime.h>
#include <cmath>

// LightGlue forward. All GEMMs + attention in bf16 MFMA. Q/K/V written bf16
// head-major directly by the qkv GEMM epilogue (RoPE fused via lane-shuffle,
// weights column-permuted at the one-time transpose). msg and LN+GELU outputs
// stored bf16 by their producers. Wo folded into W1 (Wf = Wo@W1b).
// Residual stream kept in fp32 x + bf16 mirror xb (written by the same
// producers). Assignment-head md stored bf16.
// JOURNAL (closed families, measured):
//  - coop mega-kernel grid.sync: ~100us/sync @512WG (r5, 430us/layer-half).
//  - LN+GELU+FFN2 fusion: r1 +95us (occupancy-starved serial LN),
//    r7 +175us (direct-global B, 128 blocks), r8 +33us (traffic amp:
//    B-tile re-reads x2 + LN redundancy x4 > boundary saving ~2.5us).
//  => kernel boundary ~2-3us is CHEAPER than any fusion's traffic cost here.
// N=1024, D=256, H=4, DH=64, L=9. Batched over both images (M=2048).
#define NTOK 1024
#define DM   256
#define NH   4
#define DH   64
#define NL   9

typedef __attribute__((ext_vector_type(8))) __bf16 bf16x8;
typedef __attribute__((ext_vector_type(4))) __bf16 bf16x4;
typedef __attribute__((ext_vector_type(4))) float  f32x4;

__device__ __forceinline__ float logsigf(float x) {
    return fminf(x, 0.0f) - log1pf(expf(-fabsf(x)));
}

__device__ __forceinline__ __bf16 f2bf(float f) {
    unsigned u = __float_as_uint(f);
    u = (u + 0x7FFFu + ((u >> 16) & 1u)) >> 16;          // round-nearest-even
    unsigned short s = (unsigned short)u;
    return __builtin_bit_cast(__bf16, s);
}

// ---------------------------------------------------------------------------
// All weight transposes in ONE dispatch. fp32 [K][N] (batched) -> bf16 [N][K].
// For the qkv group (z<9) output rows are PERMUTED: n' = t*256 + h*64 + d
// (orig n = h*192 + d*3 + t) so the GEMM tile maps 1:1 to (type, head).
// Grid (24, 16, 82).
// ---------------------------------------------------------------------------
__global__ __launch_bounds__(256) void wtrans_all_k(
    const float* __restrict__ sWqkv, const float* __restrict__ sWo,
    const float* __restrict__ sfW1,  const float* __restrict__ sfW2,
    const float* __restrict__ cWqk,  const float* __restrict__ cWv,
    const float* __restrict__ cWo,   const float* __restrict__ cfW1,
    const float* __restrict__ cfW2,  const float* __restrict__ mWp,
    __bf16* __restrict__ wb)
{
    const int z = blockIdx.z;
    const float* src; __bf16* dst; int K, N, b;
    if      (z <  9) { src = sWqkv; dst = wb;            K = 256; N = 768; b = z;      }
    else if (z < 18) { src = sWo;   dst = wb + 1769472;  K = 256; N = 256; b = z - 9;  }
    else if (z < 27) { src = sfW1;  dst = wb + 2359296;  K = 512; N = 512; b = z - 18; }
    else if (z < 36) { src = sfW2;  dst = wb + 4718592;  K = 512; N = 256; b = z - 27; }
    else if (z < 45) { src = cWqk;  dst = wb + 5898240;  K = 256; N = 256; b = z - 36; }
    else if (z < 54) { src = cWv;   dst = wb + 6488064;  K = 256; N = 256; b = z - 45; }
    else if (z < 63) { src = cWo;   dst = wb + 7077888;  K = 256; N = 256; b = z - 54; }
    else if (z < 72) { src = cfW1;  dst = wb + 7667712;  K = 512; N = 512; b = z - 63; }
    else if (z < 81) { src = cfW2;  dst = wb + 10027008; K = 512; N = 256; b = z - 72; }
    else             { src = mWp;   dst = wb + 11206656; K = 256; N = 256; b = 0;      }
    const int n0 = blockIdx.x * 32, k0 = blockIdx.y * 32;
    if (n0 >= N || k0 >= K) return;
    src += (size_t)b * K * N;
    dst += (size_t)b * K * N;

    __shared__ __bf16 t[32][36];
    const int tx = threadIdx.x & 31, ty = threadIdx.x >> 5;
    #pragma unroll
    for (int i = 0; i < 4; ++i) {
        int k = ty + i * 8;
        t[tx][k] = f2bf(src[(size_t)(k0 + k) * N + n0 + tx]);
    }
    __syncthreads();
    const int nr = threadIdx.x >> 3, kc = (threadIdx.x & 7) * 4;
    bf16x4 v = *(const bf16x4*)&t[nr][kc];
    int outr = n0 + nr;
    if (z < 9) {
        int h = outr / 192, r = outr % 192;
        outr = (r % 3) * 256 + h * 64 + (r / 3);
    }
    *(bf16x4*)&dst[(size_t)outr * K + k0 + kc] = v;
}

// ---------------------------------------------------------------------------
// Weight fusion: tW1f[z][o][0:256] = tW1[z][o][0:256] (copy, bx<4);
// tW1f[z][o][256+k] = sum_m tW1[z][o][256+m] * tWo[z][m][k]  (bx>=4, MFMA).
// ---------------------------------------------------------------------------
__global__ __launch_bounds__(256) void wfuse_k(
    const __bf16* __restrict__ tW1s, const __bf16* __restrict__ tWos,
    const __bf16* __restrict__ tW1c, const __bf16* __restrict__ tWoc,
    __bf16* __restrict__ tW1f)
{
    const int z = blockIdx.z, bx = blockIdx.x, tid = threadIdx.x;
    const __bf16* A  = (z < 9) ? tW1s + (size_t)z * 262144 : tW1c + (size_t)(z - 9) * 262144;
    const __bf16* B  = (z < 9) ? tWos + (size_t)z * 65536  : tWoc + (size_t)(z - 9) * 65536;
    __bf16* dst      = tW1f + (size_t)z * 262144;
    const int row0 = blockIdx.y * 32;

    if (bx < 4) {
        const int row = tid >> 3, kc = (tid & 7) * 8;
        bf16x8 v = *(const bf16x8*)&A[(size_t)(row0 + row) * 512 + bx * 64 + kc];
        *(bf16x8*)&dst[(size_t)(row0 + row) * 512 + bx * 64 + kc] = v;
        return;
    }

    __shared__ __bf16 As[8][32][40];
    __shared__ __bf16 Bs[8][64][40];
    const int w = tid >> 6, l = tid & 63;
    const int col0 = (bx - 4) * 64;
    const int wr = (w >> 1) * 16, wc = (w & 1) * 32;
    f32x4 acc0 = {0.f, 0.f, 0.f, 0.f};
    f32x4 acc1 = {0.f, 0.f, 0.f, 0.f};

    const int ar = tid >> 3, ac = (tid & 7) * 4;
    const int tnr = tid >> 3, tkc = (tid & 7) * 8;

    #pragma unroll
    for (int c = 0; c < 8; ++c) {
        bf16x4 av = *(const bf16x4*)&A[(size_t)(row0 + ar) * 512 + 256 + c * 32 + ac];
        *(bf16x4*)&As[c][ar][ac] = av;
        bf16x8 bv = *(const bf16x8*)&B[(size_t)(c * 32 + tnr) * 256 + col0 + tkc];
        #pragma unroll
        for (int e = 0; e < 8; ++e) Bs[c][tkc + e][tnr] = bv[e];
    }
    __syncthreads();
    #pragma unroll
    for (int c = 0; c < 8; ++c) {
        bf16x8 af  = *(const bf16x8*)&As[c][wr + (l & 15)][(l >> 4) * 8];
        bf16x8 bf0 = *(const bf16x8*)&Bs[c][wc + (l & 15)][(l >> 4) * 8];
        bf16x8 bf1 = *(const bf16x8*)&Bs[c][wc + 16 + (l & 15)][(l >> 4) * 8];
        acc0 = __builtin_amdgcn_mfma_f32_16x16x32_bf16(af, bf0, acc0, 0, 0, 0);
        acc1 = __builtin_amdgcn_mfma_f32_16x16x32_bf16(af, bf1, acc1, 0, 0, 0);
    }
    #pragma unroll
    for (int t2 = 0; t2 < 2; ++t2) {
        f32x4 a = t2 ? acc1 : acc0;
        int cc = col0 + wc + t2 * 16 + (l & 15);
        #pragma unroll
        for (int rg = 0; rg < 4; ++rg) {
            int rr = row0 + wr + (l >> 4) * 4 + rg;
            dst[(size_t)rr * 512 + 256 + cc] = f2bf(a[rg]);
        }
    }
}

// bfused[z][o] = b1[z][o] + sum_m bo[z][m] * W1[z][256+m][o]   (fp32)
__global__ __launch_bounds__(256) void bfuse_k(
    const float* __restrict__ sbo, const float* __restrict__ sfW1,
    const float* __restrict__ sfb1, const float* __restrict__ cbo,
    const float* __restrict__ cfW1, const float* __restrict__ cfb1,
    float* __restrict__ bf)
{
    const int z = blockIdx.y;
    const float* bo = (z < 9) ? sbo + z * 256 : cbo + (z - 9) * 256;
    const float* W1 = (z < 9) ? sfW1 + (size_t)z * 262144 : cfW1 + (size_t)(z - 9) * 262144;
    const float* b1 = (z < 9) ? sfb1 + z * 512 : cfb1 + (z - 9) * 512;
    const int o = blockIdx.x * 256 + threadIdx.x;
    float acc = 0.f;
    for (int m = 0; m < 256; ++m)
        acc += bo[m] * W1[(size_t)(256 + m) * 512 + o];
    bf[(size_t)z * 512 + o] = b1[o] + acc;
}

// ---------------------------------------------------------------------------
// qkv GEMM with fused RoPE + head-major bf16 store. A = bf16 xb [2048][256].
// K=256, Nn=768 (permuted: col' = t*256 + h*64 + d). Grid (12, 64).
// RoPE pair d^1 lives in the adjacent column = lane^1 -> __shfl_xor.
// ---------------------------------------------------------------------------
__global__ __launch_bounds__(256) void gemm_qkv_k(
    const __bf16* __restrict__ Ab, const __bf16* __restrict__ Bt,
    const float* __restrict__ bias,   // original order [768]
    const float* __restrict__ encc, const float* __restrict__ encs,
    __bf16* __restrict__ qh, __bf16* __restrict__ kh, __bf16* __restrict__ vh)
{
    __shared__ __bf16 As[8][32][40];
    __shared__ __bf16 Bs[8][64][40];
    const int tid = threadIdx.x;
    const int w = tid >> 6, l = tid & 63;
    const int row0 = blockIdx.y * 32, col0 = blockIdx.x * 64;
    const int wr = (w >> 1) * 16, wc = (w & 1) * 32;
    const int quad = l >> 4, l16 = l & 15;
    f32x4 acc0 = {0.f, 0.f, 0.f, 0.f};
    f32x4 acc1 = {0.f, 0.f, 0.f, 0.f};

    const int ar = tid >> 3, ac = (tid & 7) * 4;
    const int bnr = tid >> 2, bkc = (tid & 3) * 8;

    #pragma unroll
    for (int c = 0; c < 8; ++c) {
        const int k0 = c * 32;
        bf16x4 av = *(const bf16x4*)&Ab[(size_t)(row0 + ar) * 256 + k0 + ac];
        *(bf16x4*)&As[c][ar][ac] = av;
        bf16x8 bv = *(const bf16x8*)&Bt[(size_t)(col0 + bnr) * 256 + k0 + bkc];
        *(bf16x8*)&Bs[c][bnr][bkc] = bv;
    }
    __syncthreads();
    #pragma unroll
    for (int c = 0; c < 8; ++c) {
        bf16x8 af  = *(const bf16x8*)&As[c][wr + l16][quad * 8];
        bf16x8 bf0 = *(const bf16x8*)&Bs[c][wc + l16][quad * 8];
        bf16x8 bf1 = *(const bf16x8*)&Bs[c][wc + 16 + l16][quad * 8];
        acc0 = __builtin_amdgcn_mfma_f32_16x16x32_bf16(af, bf0, acc0, 0, 0, 0);
        acc1 = __builtin_amdgcn_mfma_f32_16x16x32_bf16(af, bf1, acc1, 0, 0, 0);
    }

    // ---- epilogue: bias + RoPE (q,k) + head-major bf16 store ----
    const int typ = col0 >> 8;            // 0=q 1=k 2=v
    const int hh  = (col0 & 255) >> 6;
    __bf16* dst = (typ == 0) ? qh : (typ == 1) ? kh : vh;
    #pragma unroll
    for (int t2 = 0; t2 < 2; ++t2) {
        f32x4 a = t2 ? acc1 : acc0;
        const int d = wc + t2 * 16 + l16;
        const float bvv = bias[hh * 192 + d * 3 + typ];
        float full[4], pair[4];
        #pragma unroll
        for (int rg = 0; rg < 4; ++rg) full[rg] = a[rg] + bvv;
        #pragma unroll
        for (int rg = 0; rg < 4; ++rg) pair[rg] = __shfl_xor(full[rg], 1);
        const float sgn = (d & 1) ? 1.0f : -1.0f;
        #pragma unroll
        for (int rg = 0; rg < 4; ++rg) {
            int rr = row0 + wr + quad * 4 + rg;
            float outv;
            if (typ == 2) {
                outv = full[rg];
            } else {
                float c = encc[(size_t)rr * 64 + d];
                float s = encs[(size_t)rr * 64 + d];
                outv = full[rg] * c + sgn * pair[rg] * s;
            }
            int im = rr >> 10, n = rr & 1023;
            dst[(((size_t)(im * 4 + hh)) * 1024 + n) * 64 + d] = f2bf(outv);
        }
    }
}

// ---------------------------------------------------------------------------
// Deep-staged bf16-MFMA GEMM: C = (A @ B + bias)*scale. bf16 A (ld 256,
// cols<256), OPTIONAL bf16 A1b (cols>=256, ld 256). bf16 B [Nn][K]. fp32 C.
// ---------------------------------------------------------------------------
__global__ __launch_bounds__(256) void gemm_bf_k(
    const __bf16* __restrict__ Ab, const __bf16* __restrict__ A1b,
    const __bf16* __restrict__ Bt, const float* __restrict__ bias,
    float* __restrict__ C, int K, int Nn, int ldc, float scale)
{
    __shared__ __bf16 As[8][32][40];
    __shared__ __bf16 Bs[8][64][40];
    const int tid = threadIdx.x;
    const int w = tid >> 6, l = tid & 63;
    const int row0 = blockIdx.y * 32, col0 = blockIdx.x * 64;
    const int wr = (w >> 1) * 16, wc = (w & 1) * 32;
    f32x4 acc0 = {0.f, 0.f, 0.f, 0.f};
    f32x4 acc1 = {0.f, 0.f, 0.f, 0.f};

    const int ar = tid >> 3, ac = (tid & 7) * 4;
    const int bnr = tid >> 2, bkc = (tid & 3) * 8;

    for (int p0 = 0; p0 < K; p0 += 256) {
        #pragma unroll
        for (int c = 0; c < 8; ++c) {
            const int k0 = p0 + c * 32;
            const int kk = k0 + ac;
            const __bf16* src = (A1b && kk >= 256)
                ? &A1b[(size_t)(row0 + ar) * 256 + (kk - 256)]
                : &Ab[(size_t)(row0 + ar) * 256 + kk];
            bf16x4 av = *(const bf16x4*)src;
            *(bf16x4*)&As[c][ar][ac] = av;
            bf16x8 bv = *(const bf16x8*)&Bt[(size_t)(col0 + bnr) * K + k0 + bkc];
            *(bf16x8*)&Bs[c][bnr][bkc] = bv;
        }
        __syncthreads();
        #pragma unroll
        for (int c = 0; c < 8; ++c) {
            bf16x8 af  = *(const bf16x8*)&As[c][wr + (l & 15)][(l >> 4) * 8];
            bf16x8 bf0 = *(const bf16x8*)&Bs[c][wc + (l & 15)][(l >> 4) * 8];
            bf16x8 bf1 = *(const bf16x8*)&Bs[c][wc + 16 + (l & 15)][(l >> 4) * 8];
            acc0 = __builtin_amdgcn_mfma_f32_16x16x32_bf16(af, bf0, acc0, 0, 0, 0);
            acc1 = __builtin_amdgcn_mfma_f32_16x16x32_bf16(af, bf1, acc1, 0, 0, 0);
        }
        __syncthreads();
    }

    #pragma unroll
    for (int t2 = 0; t2 < 2; ++t2) {
        f32x4 a = t2 ? acc1 : acc0;
        int cc = col0 + wc + t2 * 16 + (l & 15);
        float bvv = bias ? bias[cc] : 0.0f;
        #pragma unroll
        for (int rg = 0; rg < 4; ++rg) {
            int rr = row0 + wr + (l >> 4) * 4 + rg;
            C[(size_t)rr * ldc + cc] = (a[rg] + bvv) * scale;
        }
    }
}

// ---------------------------------------------------------------------------
// Head projection GEMM with bf16 output: Cb = f2bf((A @ B + bias)*scale).
// bf16 A [M][256], bf16 B [Nn][256], K=256 single phase. Grid (4, 64).
// ---------------------------------------------------------------------------
__global__ __launch_bounds__(256) void gemm_bfb_k(
    const __bf16* __restrict__ Ab, const __bf16* __restrict__ Bt,
    const float* __restrict__ bias, __bf16* __restrict__ Cb, float scale)
{
    __shared__ __bf16 As[8][32][40];
    __shared__ __bf16 Bs[8][64][40];
    const int tid = threadIdx.x;
    const int w = tid >> 6, l = tid & 63;
    const int row0 = blockIdx.y * 32, col0 = blockIdx.x * 64;
    const int wr = (w >> 1) * 16, wc = (w & 1) * 32;
    f32x4 acc0 = {0.f, 0.f, 0.f, 0.f};
    f32x4 acc1 = {0.f, 0.f, 0.f, 0.f};

    const int ar = tid >> 3, ac = (tid & 7) * 4;
    const int bnr = tid >> 2, bkc = (tid & 3) * 8;

    #pragma unroll
    for (int c = 0; c < 8; ++c) {
        const int k0 = c * 32;
        bf16x4 av = *(const bf16x4*)&Ab[(size_t)(row0 + ar) * 256 + k0 + ac];
        *(bf16x4*)&As[c][ar][ac] = av;
        bf16x8 bv = *(const bf16x8*)&Bt[(size_t)(col0 + bnr) * 256 + k0 + bkc];
        *(bf16x8*)&Bs[c][bnr][bkc] = bv;
    }
    __syncthreads();
    #pragma unroll
    for (int c = 0; c < 8; ++c) {
        bf16x8 af  = *(const bf16x8*)&As[c][wr + (l & 15)][(l >> 4) * 8];
        bf16x8 bf0 = *(const bf16x8*)&Bs[c][wc + (l & 15)][(l >> 4) * 8];
        bf16x8 bf1 = *(const bf16x8*)&Bs[c][wc + 16 + (l & 15)][(l >> 4) * 8];
        acc0 = __builtin_amdgcn_mfma_f32_16x16x32_bf16(af, bf0, acc0, 0, 0, 0);
        acc1 = __builtin_amdgcn_mfma_f32_16x16x32_bf16(af, bf1, acc1, 0, 0, 0);
    }

    #pragma unroll
    for (int t2 = 0; t2 < 2; ++t2) {
        f32x4 a = t2 ? acc1 : acc0;
        int cc = col0 + wc + t2 * 16 + (l & 15);
        float bvv = bias[cc];
        #pragma unroll
        for (int rg = 0; rg < 4; ++rg) {
            int rr = row0 + wr + (l >> 4) * 4 + rg;
            Cb[(size_t)rr * 256 + cc] = f2bf((a[rg] + bvv) * scale);
        }
    }
}

// ---------------------------------------------------------------------------
// FFN2 GEMM: bf16 A [M][512], bf16 B [Nn][512], fp32 C with residual R,
// plus bf16 mirror write Cb (the xb residual mirror). K=512 (2 phases).
// Grid (Nn/64, M/32).
// ---------------------------------------------------------------------------
__global__ __launch_bounds__(256) void gemm_bfa_k(
    const __bf16* __restrict__ Ab, const __bf16* __restrict__ Bt,
    const float* __restrict__ bias, const float* __restrict__ R,
    float* __restrict__ C, __bf16* __restrict__ Cb, int Nn)
{
    __shared__ __bf16 As[8][32][40];
    __shared__ __bf16 Bs[8][64][40];
    const int tid = threadIdx.x;
    const int w = tid >> 6, l = tid & 63;
    const int row0 = blockIdx.y * 32, col0 = blockIdx.x * 64;
    const int wr = (w >> 1) * 16, wc = (w & 1) * 32;
    f32x4 acc0 = {0.f, 0.f, 0.f, 0.f};
    f32x4 acc1 = {0.f, 0.f, 0.f, 0.f};

    const int ar = tid >> 3, ac = (tid & 7) * 4;
    const int bnr = tid >> 2, bkc = (tid & 3) * 8;

    for (int p0 = 0; p0 < 512; p0 += 256) {
        #pragma unroll
        for (int c = 0; c < 8; ++c) {
            const int k0 = p0 + c * 32;
            bf16x4 av = *(const bf16x4*)&Ab[(size_t)(row0 + ar) * 512 + k0 + ac];
            *(bf16x4*)&As[c][ar][ac] = av;
            bf16x8 bv = *(const bf16x8*)&Bt[(size_t)(col0 + bnr) * 512 + k0 + bkc];
            *(bf16x8*)&Bs[c][bnr][bkc] = bv;
        }
        __syncthreads();
        #pragma unroll
        for (int c = 0; c < 8; ++c) {
            bf16x8 af  = *(const bf16x8*)&As[c][wr + (l & 15)][(l >> 4) * 8];
            bf16x8 bf0 = *(const bf16x8*)&Bs[c][wc + (l & 15)][(l >> 4) * 8];
            bf16x8 bf1 = *(const bf16x8*)&Bs[c][wc + 16 + (l & 15)][(l >> 4) * 8];
            acc0 = __builtin_amdgcn_mfma_f32_16x16x32_bf16(af, bf0, acc0, 0, 0, 0);
            acc1 = __builtin_amdgcn_mfma_f32_16x16x32_bf16(af, bf1, acc1, 0, 0, 0);
        }
        __syncthreads();
    }

    #pragma unroll
    for (int t2 = 0; t2 < 2; ++t2) {
        f32x4 a = t2 ? acc1 : acc0;
        int cc = col0 + wc + t2 * 16 + (l & 15);
        float bvv = bias[cc];
        #pragma unroll
        for (int rg = 0; rg < 4; ++rg) {
            int rr = row0 + wr + (l >> 4) * 4 + rg;
            float outv = a[rg] + bvv + R[(size_t)rr * Nn + cc];
            C[(size_t)rr * Nn + cc]  = outv;
            Cb[(size_t)rr * Nn + cc] = f2bf(outv);
        }
    }
}

// ---------------------------------------------------------------------------
// Cross qk+v fused GEMM (deep-staged, K=256): grid (8, 64). bx<4 -> Wq, else Wv.
// A = bf16 xb.
// ---------------------------------------------------------------------------
__global__ __launch_bounds__(256) void gemm_hm2_k(
    const __bf16* __restrict__ Ab, const __bf16* __restrict__ Btq,
    const float* __restrict__ bq, const __bf16* __restrict__ Btv,
    const float* __restrict__ bv, __bf16* __restrict__ outq,
    __bf16* __restrict__ outv, float scaleq)
{
    const int bx = blockIdx.x;
    const __bf16* Bt  = (bx < 4) ? Btq : Btv;
    const float* bias = (bx < 4) ? bq : bv;
    __bf16* C         = (bx < 4) ? outq : outv;
    const float scale = (bx < 4) ? scaleq : 1.0f;

    __shared__ __bf16 As[8][32][40];
    __shared__ __bf16 Bs[8][64][40];
    const int tid = threadIdx.x;
    const int w = tid >> 6, l = tid & 63;
    const int row0 = blockIdx.y * 32, col0 = (bx & 3) * 64;
    const int wr = (w >> 1) * 16, wc = (w & 1) * 32;
    f32x4 acc0 = {0.f, 0.f, 0.f, 0.f};
    f32x4 acc1 = {0.f, 0.f, 0.f, 0.f};

    const int ar = tid >> 3, ac = (tid & 7) * 4;
    const int bnr = tid >> 2, bkc = (tid & 3) * 8;

    #pragma unroll
    for (int c = 0; c < 8; ++c) {
        const int k0 = c * 32;
        bf16x4 av = *(const bf16x4*)&Ab[(size_t)(row0 + ar) * 256 + k0 + ac];
        *(bf16x4*)&As[c][ar][ac] = av;
        bf16x8 bv8 = *(const bf16x8*)&Bt[(size_t)(col0 + bnr) * 256 + k0 + bkc];
        *(bf16x8*)&Bs[c][bnr][bkc] = bv8;
    }
    __syncthreads();
    #pragma unroll
    for (int c = 0; c < 8; ++c) {
        bf16x8 af  = *(const bf16x8*)&As[c][wr + (l & 15)][(l >> 4) * 8];
        bf16x8 bf0 = *(const bf16x8*)&Bs[c][wc + (l & 15)][(l >> 4) * 8];
        bf16x8 bf1 = *(const bf16x8*)&Bs[c][wc + 16 + (l & 15)][(l >> 4) * 8];
        acc0 = __builtin_amdgcn_mfma_f32_16x16x32_bf16(af, bf0, acc0, 0, 0, 0);
        acc1 = __builtin_amdgcn_mfma_f32_16x16x32_bf16(af, bf1, acc1, 0, 0, 0);
    }

    #pragma unroll
    for (int t2 = 0; t2 < 2; ++t2) {
        f32x4 a = t2 ? acc1 : acc0;
        int cc = col0 + wc + t2 * 16 + (l & 15);
        float bvv = bias ? bias[cc] : 0.0f;
        int h = cc >> 6, d = cc & 63;
        #pragma unroll
        for (int rg = 0; rg < 4; ++rg) {
            int rr = row0 + wr + (l >> 4) * 4 + rg;
            int im = rr >> 10, n = rr & 1023;
            C[(((size_t)(im * 4 + h)) * 1024 + n) * 64 + d] = f2bf((a[rg] + bvv) * scale);
        }
    }
}

// ---------------------------------------------------------------------------
// sim = A @ B^T, bf16 A,B (mdb halves), K=256 single phase, fp32 C.
// Grid (16, 32).
// ---------------------------------------------------------------------------
__global__ __launch_bounds__(256) void gemm_bt_k(
    const __bf16* __restrict__ Ab, const __bf16* __restrict__ Bb,
    float* __restrict__ C, int Nn)
{
    __shared__ __bf16 As[8][32][40];
    __shared__ __bf16 Bs[8][64][40];
    const int tid = threadIdx.x;
    const int w = tid >> 6, l = tid & 63;
    const int row0 = blockIdx.y * 32, col0 = blockIdx.x * 64;
    const int wr = (w >> 1) * 16, wc = (w & 1) * 32;
    f32x4 acc0 = {0.f, 0.f, 0.f, 0.f};
    f32x4 acc1 = {0.f, 0.f, 0.f, 0.f};

    const int ar = tid >> 3, ac = (tid & 7) * 4;
    const int bnr = tid >> 2, bkc = (tid & 3) * 8;

    #pragma unroll
    for (int c = 0; c < 8; ++c) {
        const int k0 = c * 32;
        bf16x4 av = *(const bf16x4*)&Ab[(size_t)(row0 + ar) * 256 + k0 + ac];
        *(bf16x4*)&As[c][ar][ac] = av;
        bf16x8 bv = *(const bf16x8*)&Bb[(size_t)(col0 + bnr) * 256 + k0 + bkc];
        *(bf16x8*)&Bs[c][bnr][bkc] = bv;
    }
    __syncthreads();
    #pragma unroll
    for (int c = 0; c < 8; ++c) {
        bf16x8 af  = *(const bf16x8*)&As[c][wr + (l & 15)][(l >> 4) * 8];
        bf16x8 bf0 = *(const bf16x8*)&Bs[c][wc + (l & 15)][(l >> 4) * 8];
        bf16x8 bf1 = *(const bf16x8*)&Bs[c][wc + 16 + (l & 15)][(l >> 4) * 8];
        acc0 = __builtin_amdgcn_mfma_f32_16x16x32_bf16(af, bf0, acc0, 0, 0, 0);
        acc1 = __builtin_amdgcn_mfma_f32_16x16x32_bf16(af, bf1, acc1, 0, 0, 0);
    }

    #pragma unroll
    for (int t2 = 0; t2 < 2; ++t2) {
        f32x4 a = t2 ? acc1 : acc0;
        int cc = col0 + wc + t2 * 16 + (l & 15);
        #pragma unroll
        for (int rg = 0; rg < 4; ++rg) {
            int rr = row0 + wr + (l >> 4) * 4 + rg;
            C[(size_t)rr * Nn + cc] = a[rg];
        }
    }
}

// ---------------------------------------------------------------------------
// Fused init: desc copies (fp32 + bf16 mirror) + posenc. Grid 2304 x 256.
// ---------------------------------------------------------------------------
__global__ __launch_bounds__(256) void init_k(
    const float* __restrict__ desc0, const float* __restrict__ desc1,
    const float* __restrict__ kpts0, const float* __restrict__ kpts1,
    const float* __restrict__ Wr, float* __restrict__ x,
    __bf16* __restrict__ xb,
    float* __restrict__ encc, float* __restrict__ encs)
{
    int idx = blockIdx.x * 256 + threadIdx.x;
    if (idx < 524288) {
        float v = (idx < 262144) ? desc0[idx] : desc1[idx - 262144];
        x[idx]  = v;
        xb[idx] = f2bf(v);
    } else {
        int p = idx - 524288;
        int im = p >> 15, q = p & 32767;
        int i = q >> 5, f = q & 31;
        const float* kp = im ? kpts1 : kpts0;
        float* ec = encc + im * 65536;
        float* es = encs + im * 65536;
        float pr = kp[i * 2] * Wr[f] + kp[i * 2 + 1] * Wr[32 + f];
        float c = cosf(pr), s = sinf(pr);
        ec[i * 64 + 2 * f] = c; ec[i * 64 + 2 * f + 1] = c;
        es[i * 64 + 2 * f] = s; es[i * 64 + 2 * f + 1] = s;
    }
}

// ---------------------------------------------------------------------------
// Attention v6: flash-style bf16 MFMA with K/V register prefetch pipelining.
// Output msg written bf16 [2048][256].
// ---------------------------------------------------------------------------
__global__ __launch_bounds__(256) void attn_k(
    const __bf16* __restrict__ Qg, const __bf16* __restrict__ Kg,
    const __bf16* __restrict__ Vg, __bf16* __restrict__ out,
    float scale, int cross)
{
    const int qt = blockIdx.x, hv = blockIdx.y;
    const int kvh = cross ? (hv ^ 4) : hv;
    const int tid = threadIdx.x;
    const int w = tid >> 6, lane = tid & 63;
    const int quad = lane >> 4, l16 = lane & 15;
    const int n0 = qt * 16;

    __shared__ __align__(16) char smem[44032];
    char* base = smem + w * 11008;
    __bf16* kb  = (__bf16*)(base);          // 32 x 72
    __bf16* vtb = (__bf16*)(base + 4608);   // 64 x 40
    __bf16* ptb = (__bf16*)(base + 9728);   // 16 x 40

    bf16x8 qf[2];
    {
        const bf16x8* Qp = (const bf16x8*)(Qg + (((size_t)hv * 1024) + n0 + l16) * 64);
        qf[0] = Qp[quad];
        qf[1] = Qp[4 + quad];
    }

    const __bf16* Kbase = Kg + (size_t)kvh * 1024 * 64;
    const __bf16* Vbase = Vg + (size_t)kvh * 1024 * 64;

    float m[4] = {-1e30f, -1e30f, -1e30f, -1e30f};
    float lsum[4] = {0.f, 0.f, 0.f, 0.f};
    f32x4 o[4] = {{0,0,0,0},{0,0,0,0},{0,0,0,0},{0,0,0,0}};

    const int kj = lane >> 1, kd = (lane & 1) * 32;
    const int vjp = lane & 15, vd0 = (lane >> 4) * 16;

    bf16x8 kr[4];
    uint4  vr[4];
    {
        const int j0 = w * 256;
        const bf16x8* kp = (const bf16x8*)(Kbase + (size_t)(j0 + kj) * 64 + kd);
        kr[0] = kp[0]; kr[1] = kp[1]; kr[2] = kp[2]; kr[3] = kp[3];
        const uint4* va = (const uint4*)(Vbase + (size_t)(j0 + 2 * vjp) * 64 + vd0);
        const uint4* vb = (const uint4*)(Vbase + (size_t)(j0 + 2 * vjp + 1) * 64 + vd0);
        vr[0] = va[0]; vr[1] = va[1]; vr[2] = vb[0]; vr[3] = vb[1];
    }

    for (int t = 0; t < 8; ++t) {
        {
            __bf16* krow = kb + kj * 72 + kd;
            *(bf16x8*)(krow)      = kr[0];
            *(bf16x8*)(krow + 8)  = kr[1];
            *(bf16x8*)(krow + 16) = kr[2];
            *(bf16x8*)(krow + 24) = kr[3];
            #pragma unroll
            for (int g = 0; g < 2; ++g) {
                uint4 ua = vr[g], ub = vr[2 + g];
                unsigned au[4] = {ua.x, ua.y, ua.z, ua.w};
                unsigned bu[4] = {ub.x, ub.y, ub.z, ub.w};
                #pragma unroll
                for (int e = 0; e < 4; ++e) {
                    int i = g * 8 + e * 2;
                    unsigned pk0 = ((bu[e] & 0xFFFFu) << 16) | (au[e] & 0xFFFFu);
                    unsigned pk1 = (bu[e] & 0xFFFF0000u) | (au[e] >> 16);
                    *(unsigned*)((char*)vtb + ((vd0 + i) * 40 + 2 * vjp) * 2)     = pk0;
                    *(unsigned*)((char*)vtb + ((vd0 + i + 1) * 40 + 2 * vjp) * 2) = pk1;
                }
            }
        }
        if (t < 7) {
            const int j1 = w * 256 + (t + 1) * 32;
            const bf16x8* kp = (const bf16x8*)(Kbase + (size_t)(j1 + kj) * 64 + kd);
            kr[0] = kp[0]; kr[1] = kp[1]; kr[2] = kp[2]; kr[3] = kp[3];
            const uint4* va = (const uint4*)(Vbase + (size_t)(j1 + 2 * vjp) * 64 + vd0);
            const uint4* vb = (const uint4*)(Vbase + (size_t)(j1 + 2 * vjp + 1) * 64 + vd0);
            vr[0] = va[0]; vr[1] = va[1]; vr[2] = vb[0]; vr[3] = vb[1];
        }

        f32x4 s0 = {0,0,0,0}, s1 = {0,0,0,0};
        #pragma unroll
        for (int kt = 0; kt < 2; ++kt) {
            bf16x8 k0 = *(const bf16x8*)(kb + (0 * 16 + l16) * 72 + kt * 32 + quad * 8);
            bf16x8 k1 = *(const bf16x8*)(kb + (1 * 16 + l16) * 72 + kt * 32 + quad * 8);
            s0 = __builtin_amdgcn_mfma_f32_16x16x32_bf16(qf[kt], k0, s0, 0, 0, 0);
            s1 = __builtin_amdgcn_mfma_f32_16x16x32_bf16(qf[kt], k1, s1, 0, 0, 0);
        }

        float rm[4], p0[4], p1[4], rs[4];
        #pragma unroll
        for (int r = 0; r < 4; ++r) {
            s0[r] *= scale; s1[r] *= scale;
            rm[r] = fmaxf(s0[r], s1[r]);
        }
        #pragma unroll
        for (int ofs = 1; ofs < 16; ofs <<= 1)
            #pragma unroll
            for (int r = 0; r < 4; ++r)
                rm[r] = fmaxf(rm[r], __shfl_xor(rm[r], ofs));
        #pragma unroll
        for (int r = 0; r < 4; ++r) {
            float mn = fmaxf(m[r], rm[r]);
            float alpha = __expf(m[r] - mn);
            m[r] = mn;
            p0[r] = __expf(s0[r] - mn);
            p1[r] = __expf(s1[r] - mn);
            rs[r] = p0[r] + p1[r];
            lsum[r] *= alpha;
            #pragma unroll
            for (int dt = 0; dt < 4; ++dt) o[dt][r] *= alpha;
        }
        #pragma unroll
        for (int ofs = 1; ofs < 16; ofs <<= 1)
            #pragma unroll
            for (int r = 0; r < 4; ++r)
                rs[r] += __shfl_xor(rs[r], ofs);
        #pragma unroll
        for (int r = 0; r < 4; ++r) lsum[r] += rs[r];

        #pragma unroll
        for (int r = 0; r < 4; ++r) {
            ptb[(quad * 4 + r) * 40 + l16]      = f2bf(p0[r]);
            ptb[(quad * 4 + r) * 40 + 16 + l16] = f2bf(p1[r]);
        }
        bf16x8 pf = *(const bf16x8*)(ptb + l16 * 40 + quad * 8);
        #pragma unroll
        for (int dt = 0; dt < 4; ++dt) {
            bf16x8 vf = *(const bf16x8*)(vtb + (dt * 16 + l16) * 40 + quad * 8);
            o[dt] = __builtin_amdgcn_mfma_f32_16x16x32_bf16(pf, vf, o[dt], 0, 0, 0);
        }
    }

    __syncthreads();
    float* Om = (float*)smem;          // [64][64] : row = w*16 + q
    float* mm = Om + 4096;             // [64]
    float* lm = mm + 64;               // [64]
    #pragma unroll
    for (int dt = 0; dt < 4; ++dt)
        #pragma unroll
        for (int r = 0; r < 4; ++r)
            Om[(w * 16 + quad * 4 + r) * 64 + dt * 16 + l16] = o[dt][r];
    if (l16 == 0) {
        #pragma unroll
        for (int r = 0; r < 4; ++r) {
            mm[w * 16 + quad * 4 + r] = m[r];
            lm[w * 16 + quad * 4 + r] = lsum[r];
        }
    }
    __syncthreads();

    const int q = tid >> 4, dg = tid & 15;
    float M = -1e30f;
    #pragma unroll
    for (int w2 = 0; w2 < 4; ++w2) M = fmaxf(M, mm[w2 * 16 + q]);
    float L = 0.f;
    float4 acc = {0.f, 0.f, 0.f, 0.f};
    #pragma unroll
    for (int w2 = 0; w2 < 4; ++w2) {
        float e = __expf(mm[w2 * 16 + q] - M);
        L += e * lm[w2 * 16 + q];
        float4 ov = *(const float4*)&Om[(w2 * 16 + q) * 64 + dg * 4];
        acc.x += e * ov.x; acc.y += e * ov.y; acc.z += e * ov.z; acc.w += e * ov.w;
    }
    float inv = 1.0f / L;
    bf16x4 ob;
    ob[0] = f2bf(acc.x * inv); ob[1] = f2bf(acc.y * inv);
    ob[2] = f2bf(acc.z * inv); ob[3] = f2bf(acc.w * inv);
    int row = (hv >> 2) * 1024 + n0 + q;
    *(bf16x4*)&out[(size_t)row * 256 + (hv & 3) * 64 + dg * 4] = ob;
}

// ---------------------------------------------------------------------------
// LayerNorm (512) + exact GELU, wave-per-row, fp32 in -> bf16 out.
// ---------------------------------------------------------------------------
__global__ __launch_bounds__(256) void lngelu_k(
    const float* __restrict__ x, __bf16* __restrict__ outb,
    const float* __restrict__ g, const float* __restrict__ beta)
{
    int row = blockIdx.x * 4 + (threadIdx.x >> 6);
    int lane = threadIdx.x & 63;
    const float* xr = x + (size_t)row * 512;
    __bf16* ob = outb + (size_t)row * 512;
    float4 v0 = *(const float4*)&xr[lane * 4];
    float4 v1 = *(const float4*)&xr[256 + lane * 4];
    float s = v0.x + v0.y + v0.z + v0.w + v1.x + v1.y + v1.z + v1.w;
    #pragma unroll
    for (int ofs = 1; ofs < 64; ofs <<= 1) s += __shfl_xor(s, ofs);
    float mu = s * (1.0f / 512.0f);
    float d0x = v0.x - mu, d0y = v0.y - mu, d0z = v0.z - mu, d0w = v0.w - mu;
    float d1x = v1.x - mu, d1y = v1.y - mu, d1z = v1.z - mu, d1w = v1.w - mu;
    float vv = d0x*d0x + d0y*d0y + d0z*d0z + d0w*d0w
             + d1x*d1x + d1y*d1y + d1z*d1z + d1w*d1w;
    #pragma unroll
    for (int ofs = 1; ofs < 64; ofs <<= 1) vv += __shfl_xor(vv, ofs);
    float rstd = rsqrtf(vv * (1.0f / 512.0f) + 1e-5f);
    const float IS2 = 0.70710678118654752f;
    bf16x4 o0, o1;
    {
        float4 gg = *(const float4*)&g[lane * 4];
        float4 bb = *(const float4*)&beta[lane * 4];
        float y;
        y = d0x * rstd * gg.x + bb.x; o0[0] = f2bf(0.5f * y * (1.0f + erff(y * IS2)));
        y = d0y * rstd * gg.y + bb.y; o0[1] = f2bf(0.5f * y * (1.0f + erff(y * IS2)));
        y = d0z * rstd * gg.z + bb.z; o0[2] = f2bf(0.5f * y * (1.0f + erff(y * IS2)));
        y = d0w * rstd * gg.w + bb.w; o0[3] = f2bf(0.5f * y * (1.0f + erff(y * IS2)));
    }
    {
        float4 gg = *(const float4*)&g[256 + lane * 4];
        float4 bb = *(const float4*)&beta[256 + lane * 4];
        float y;
        y = d1x * rstd * gg.x + bb.x; o1[0] = f2bf(0.5f * y * (1.0f + erff(y * IS2)));
        y = d1y * rstd * gg.y + bb.y; o1[1] = f2bf(0.5f * y * (1.0f + erff(y * IS2)));
        y = d1z * rstd * gg.z + bb.z; o1[2] = f2bf(0.5f * y * (1.0f + erff(y * IS2)));
        y = d1w * rstd * gg.w + bb.w; o1[3] = f2bf(0.5f * y * (1.0f + erff(y * IS2)));
    }
    *(bf16x4*)&ob[lane * 4]       = o0;
    *(bf16x4*)&ob[256 + lane * 4] = o1;
}

// z = x @ Wz + bz : wave-per-row, float4 + shfl reduce. Grid 512.
__global__ __launch_bounds__(256) void z_k(
    const float* __restrict__ x, const float* __restrict__ Wz,
    const float* __restrict__ bz, float* __restrict__ z)
{
    int row = blockIdx.x * 4 + (threadIdx.x >> 6);
    int lane = threadIdx.x & 63;
    float4 v  = *(const float4*)&x[(size_t)row * 256 + lane * 4];
    float4 wv = *(const float4*)&Wz[lane * 4];
    float s = v.x * wv.x + v.y * wv.y + v.z * wv.z + v.w * wv.w;
    #pragma unroll
    for (int ofs = 1; ofs < 64; ofs <<= 1) s += __shfl_xor(s, ofs);
    if (lane == 0) z[row] = s + bz[0];
}

// Row lse (blocks 0..1023) and col lse (blocks 1024..2047) in one dispatch.
__global__ __launch_bounds__(256) void lse_k(
    const float* __restrict__ sim, float* __restrict__ rls,
    float* __restrict__ cls)
{
    const int b = blockIdx.x, t = threadIdx.x;
    const int isCol = b >> 10, rc = b & 1023;
    const size_t base = isCol ? (size_t)rc : (size_t)rc * 1024;
    const size_t stride = isCol ? 1024 : 1;
    __shared__ float red[256];
    float mx = -1e30f;
    for (int j = t; j < NTOK; j += 256) mx = fmaxf(mx, sim[base + stride * j]);
    red[t] = mx; __syncthreads();
    for (int s = 128; s > 0; s >>= 1) {
        if (t < s) red[t] = fmaxf(red[t], red[t + s]);
        __syncthreads();
    }
    mx = red[0]; __syncthreads();
    float sum = 0.0f;
    for (int j = t; j < NTOK; j += 256) sum += expf(sim[base + stride * j] - mx);
    red[t] = sum; __syncthreads();
    for (int s = 128; s > 0; s >>= 1) {
        if (t < s) red[t] += red[t + s];
        __syncthreads();
    }
    if (t == 0) (isCol ? cls : rls)[rc] = mx + logf(red[0]);
}

__global__ __launch_bounds__(256) void assemble_k(
    const float* __restrict__ sim, const float* __restrict__ rls,
    const float* __restrict__ cls, const float* __restrict__ z0,
    const float* __restrict__ z1, float* __restrict__ out)
{
    int idx = blockIdx.x * 256 + threadIdx.x;
    const int W = NTOK + 1;
    if (idx >= W * W) return;
    int i = idx / W, j = idx % W;
    float v;
    if (i < NTOK && j < NTOK) {
        v = 2.0f * sim[(size_t)i * NTOK + j] - rls[i] - cls[j] + logsigf(z0[i]) + logsigf(z1[j]);
    } else if (i < NTOK) {
        v = logsigf(-z0[i]);
    } else if (j < NTOK) {
        v = logsigf(-z1[j]);
    } else {
        v = 0.0f;
    }
    out[idx] = v;
}

// ---------------------------------------------------------------------------
extern "C" void kernel_launch(void* const* d_in, const int* in_sizes, int n_in,
                              void* d_out, int out_size, void* d_ws, size_t ws_size,
                              hipStream_t stream)
{
    const float* desc0 = (const float*)d_in[0];
    const float* desc1 = (const float*)d_in[1];
    const float* kpts0 = (const float*)d_in[2];
    const float* kpts1 = (const float*)d_in[3];
    const float* Wr    = (const float*)d_in[4];
    const float* sWqkv = (const float*)d_in[5];
    const float* sbqkv = (const float*)d_in[6];
    const float* sWo   = (const float*)d_in[7];
    const float* sbo   = (const float*)d_in[8];
    const float* sfW1  = (const float*)d_in[9];
    const float* sfb1  = (const float*)d_in[10];
    const float* sfg   = (const float*)d_in[11];
    const float* sfbt  = (const float*)d_in[12];
    const float* sfW2  = (const float*)d_in[13];
    const float* sfb2  = (const float*)d_in[14];
    const float* cWqk  = (const float*)d_in[15];
    const float* cbqk  = (const float*)d_in[16];
    const float* cWv   = (const float*)d_in[17];
    const float* cbv   = (const float*)d_in[18];
    const float* cWo   = (const float*)d_in[19];
    const float* cbo   = (const float*)d_in[20];
    const float* cfW1  = (const float*)d_in[21];
    const float* cfb1  = (const float*)d_in[22];
    const float* cfg   = (const float*)d_in[23];
    const float* cfbt  = (const float*)d_in[24];
    const float* cfW2  = (const float*)d_in[25];
    const float* cfb2  = (const float*)d_in[26];
    const float* mWp   = (const float*)d_in[27];
    const float* mbp   = (const float*)d_in[28];
    const float* mWz   = (const float*)d_in[29];
    const float* mbz   = (const float*)d_in[30];

    float* ws = (float*)d_ws;
    // Layout (float units):
    float*  x    = ws;                      // 524288  [2048][256] fp32
    float*  encc = ws + 524288;             // 131072  [2048][64]
    float*  encs = ws + 655360;             // 131072
    float*  pre  = ws + 786432;             // 1048576 [2048][512] fp32
    __bf16* preb = (__bf16*)(ws + 1835008); // 524288 fl = [2048][512] bf16
    __bf16* qh   = (__bf16*)(ws + 2359296); // 262144 fl
    __bf16* kh   = (__bf16*)(ws + 2621440); // 262144 fl
    __bf16* vh   = (__bf16*)(ws + 2883584); // 262144 fl
    __bf16* msgb = (__bf16*)(ws + 3145728); // 131072 fl = [2048][256] bf16
    float*  zb   = ws + 3276800;            // 2048
    float*  rlsb = ws + 3278848;            // 1024
    float*  clsb = ws + 3279872;            // 1024
    float*  sim  = pre;                     // 1048576 (assignment; pre dead)
    __bf16* mdb  = (__bf16*)(ws + 1835008); // [2048][256] bf16 (assignment; preb dead)

    // bf16 pre-transposed weights [N][K]
    __bf16* wb    = (__bf16*)(ws + 3280896);
    __bf16* tWqkv = wb;                     // 9*768*256 (rows permuted t*256+h*64+d)
    __bf16* tWo   = tWqkv + 1769472;
    __bf16* tW1   = tWo   + 589824;
    __bf16* tW2   = tW1   + 2359296;
    __bf16* tcQk  = tW2   + 1179648;
    __bf16* tcV   = tcQk  + 589824;
    __bf16* tcWo  = tcV   + 589824;
    __bf16* tcW1  = tcWo  + 589824;
    __bf16* tcW2  = tcW1  + 2359296;
    __bf16* tmWp  = tcW2  + 1179648;        // 65536   (wb total 11272192 bf16)
    __bf16* tW1f  = (__bf16*)(ws + 8916992);   // 4718592 bf16 = 2359296 fl
    float*  bfb   = ws + 11276288;             // 18*512 = 9216 fl
    __bf16* xb    = (__bf16*)(ws + 11285504);  // 524288 bf16 = 262144 fl (total ~46.2 MB)

    // ---- one-time: transposes (+qkv perm), weight fusion, bias fusion ----
    wtrans_all_k<<<dim3(24, 16, 82), 256, 0, stream>>>(
        sWqkv, sWo, sfW1, sfW2, cWqk, cWv, cWo, cfW1, cfW2, mWp, wb);
    wfuse_k<<<dim3(8, 16, 18), 256, 0, stream>>>(tW1, tWo, tcW1, tcWo, tW1f);
    bfuse_k<<<dim3(2, 18), 256, 0, stream>>>(sbo, sfW1, sfb1, cbo, cfW1, cfb1, bfb);

    const float SELF_SCALE  = 0.125f;               // DH^-0.5
    const float CROSS_SCALE = 0.35355339059327373f; // DH^-0.25

    init_k<<<2304, 256, 0, stream>>>(desc0, desc1, kpts0, kpts1, Wr, x, xb, encc, encs);

    for (int l = 0; l < NL; ++l) {
        // ---- self block ----
        gemm_qkv_k<<<dim3(12, 64), 256, 0, stream>>>(
            xb, tWqkv + (size_t)l * 196608, sbqkv + (size_t)l * 768,
            encc, encs, qh, kh, vh);
        attn_k<<<dim3(64, 8), 256, 0, stream>>>(qh, kh, vh, msgb, SELF_SCALE, 0);
        gemm_bf_k<<<dim3(8, 64), 256, 0, stream>>>(
            xb, msgb, tW1f + (size_t)l * 262144, bfb + (size_t)l * 512,
            pre, 512, 512, 512, 1.0f);
        lngelu_k<<<512, 256, 0, stream>>>(pre, preb, sfg + (size_t)l * 512, sfbt + (size_t)l * 512);
        gemm_bfa_k<<<dim3(4, 64), 256, 0, stream>>>(
            preb, tW2 + (size_t)l * 131072, sfb2 + (size_t)l * 256, x, x, xb, 256);

        // ---- cross block ----
        gemm_hm2_k<<<dim3(8, 64), 256, 0, stream>>>(
            xb, tcQk + (size_t)l * 65536, cbqk + (size_t)l * 256,
            tcV + (size_t)l * 65536, cbv + (size_t)l * 256,
            qh, vh, CROSS_SCALE);
        attn_k<<<dim3(64, 8), 256, 0, stream>>>(qh, qh, vh, msgb, 1.0f, 1);
        gemm_bf_k<<<dim3(8, 64), 256, 0, stream>>>(
            xb, msgb, tW1f + (size_t)(9 + l) * 262144, bfb + (size_t)(9 + l) * 512,
            pre, 512, 512, 512, 1.0f);
        lngelu_k<<<512, 256, 0, stream>>>(pre, preb, cfg + (size_t)l * 512, cfbt + (size_t)l * 512);
        gemm_bfa_k<<<dim3(4, 64), 256, 0, stream>>>(
            preb, tcW2 + (size_t)l * 131072, cfb2 + (size_t)l * 256, x, x, xb, 256);
    }

    // ---- assignment head ----
    const float MD_SCALE = 0.25f; // D^-0.25
    gemm_bfb_k<<<dim3(4, 64), 256, 0, stream>>>(xb, tmWp, mbp, mdb, MD_SCALE);
    z_k<<<512, 256, 0, stream>>>(x, mWz, mbz, zb);
    gemm_bt_k<<<dim3(16, 32), 256, 0, stream>>>(mdb, mdb + 1024 * 256, sim, 1024);
    lse_k<<<2048, 256, 0, stream>>>(sim, rlsb, clsb);
    const int W = NTOK + 1;
    assemble_k<<<(W * W + 255) / 256, 256, 0, stream>>>(sim, rlsb, clsb, zb, zb + 1024, (float*)d_out);
}